// Round 1
// baseline (2408.212 us; speedup 1.0000x reference)
//
#include <hip/hip_runtime.h>
#include <hip/hip_bf16.h>

#define N_NODES 50000
#define N_EDGES 400000

__device__ __forceinline__ unsigned enc_f(float x) {
    unsigned u = __float_as_uint(x);
    return (u & 0x80000000u) ? ~u : (u | 0x80000000u);
}
__device__ __forceinline__ float dec_f(unsigned u) {
    return __uint_as_float((u & 0x80000000u) ? (u ^ 0x80000000u) : ~u);
}

// ---------------- GEMM: C[M,N] = A[M,K] @ B[K,N], row-major ----------------
// 64x64 tile, BK=16, 256 threads, 4x4 micro-tile per thread.
__global__ __launch_bounds__(256) void gemm64(const float* __restrict__ A,
                                              const float* __restrict__ B,
                                              float* __restrict__ C,
                                              int M, int N, int K) {
    __shared__ float As[16][68];   // [k][m], +4 pad
    __shared__ float Bs[16][68];   // [k][n], +4 pad
    const int tid = threadIdx.x;
    const int bm = blockIdx.y * 64, bn = blockIdx.x * 64;
    const int tr = tid >> 4, tc = tid & 15;
    const int ar = tid >> 2, ac = (tid & 3) * 4;  // A loader: row ar, k-offset ac
    const int br = tid >> 4, bc = (tid & 15) * 4; // B loader: k-row br, col bc
    float acc[4][4] = {};

    for (int k0 = 0; k0 < K; k0 += 16) {
        float4 av = make_float4(0.f, 0.f, 0.f, 0.f);
        if (bm + ar < M)
            av = *(const float4*)&A[(size_t)(bm + ar) * K + k0 + ac];
        As[ac + 0][ar] = av.x;
        As[ac + 1][ar] = av.y;
        As[ac + 2][ar] = av.z;
        As[ac + 3][ar] = av.w;
        float4 bv = *(const float4*)&B[(size_t)(k0 + br) * N + bn + bc];
        *(float4*)&Bs[br][bc] = bv;
        __syncthreads();
#pragma unroll
        for (int k = 0; k < 16; ++k) {
            float4 a = *(const float4*)&As[k][tr * 4];
            float4 b = *(const float4*)&Bs[k][tc * 4];
            float aa[4] = {a.x, a.y, a.z, a.w};
            float bb[4] = {b.x, b.y, b.z, b.w};
#pragma unroll
            for (int i = 0; i < 4; ++i)
#pragma unroll
                for (int j = 0; j < 4; ++j) acc[i][j] += aa[i] * bb[j];
        }
        __syncthreads();
    }
#pragma unroll
    for (int i = 0; i < 4; ++i) {
        int r = bm + tr * 4 + i;
        if (r < M) {
#pragma unroll
            for (int j = 0; j < 4; ++j)
                C[(size_t)r * N + bn + tc * 4 + j] = acc[i][j];
        }
    }
}

// ---------------- el/er: one wave per (node, head), D=64 lanes ----------------
template <int H>
__global__ __launch_bounds__(256) void eler_k(const float* __restrict__ f,
                                              const float* __restrict__ al,
                                              const float* __restrict__ ar,
                                              float* __restrict__ el,
                                              float* __restrict__ er, int N) {
    int gw = (blockIdx.x * blockDim.x + threadIdx.x) >> 6;
    int lane = threadIdx.x & 63;
    if (gw >= N * H) return;
    int h = gw % H;
    float v = f[(size_t)gw * 64 + lane];
    float pl = v * al[h * 64 + lane];
    float pr = v * ar[h * 64 + lane];
#pragma unroll
    for (int off = 32; off; off >>= 1) {
        pl += __shfl_xor(pl, off);
        pr += __shfl_xor(pr, off);
    }
    if (lane == 0) {
        el[gw] = pl;
        er[gw] = pr;
    }
}

// ---------------- edge pass 1: score + atomic segment max ----------------
template <int H>
__global__ __launch_bounds__(256) void edge_max_k(const int* __restrict__ src,
                                                  const int* __restrict__ dst,
                                                  const float* __restrict__ el,
                                                  const float* __restrict__ er,
                                                  float* __restrict__ ebuf,
                                                  unsigned* __restrict__ m, int E) {
    int i = blockIdx.x * blockDim.x + threadIdx.x;
    if (i >= E * H) return;
    int e = i / H, h = i % H;
    int s = src[e], d = dst[e];
    float v = el[s * H + h] + er[d * H + h];
    v = v > 0.f ? v : 0.2f * v;
    ebuf[i] = v;
    atomicMax(&m[d * H + h], enc_f(v));
}

// ---------------- edge pass 2: exp + atomic segment sum ----------------
template <int H>
__global__ __launch_bounds__(256) void edge_expsum_k(const int* __restrict__ dst,
                                                     float* __restrict__ ebuf,
                                                     const unsigned* __restrict__ m,
                                                     float* __restrict__ denom, int E) {
    int i = blockIdx.x * blockDim.x + threadIdx.x;
    if (i >= E * H) return;
    int e = i / H, h = i % H;
    int d = dst[e];
    float mm = dec_f(m[d * H + h]);
    float ex = __expf(ebuf[i] - mm);
    ebuf[i] = ex;
    atomicAdd(&denom[d * H + h], ex);
}

// ---------------- edge pass 3: weighted scatter-add, wave per (edge,head) ----------------
template <int H>
__global__ __launch_bounds__(256) void edge_agg_k(const float* __restrict__ f,
                                                  const float* __restrict__ ebuf,
                                                  const float* __restrict__ denom,
                                                  const int* __restrict__ src,
                                                  const int* __restrict__ dst,
                                                  float* __restrict__ rst, int E) {
    int gw = (blockIdx.x * blockDim.x + threadIdx.x) >> 6;
    int lane = threadIdx.x & 63;
    if (gw >= E * H) return;
    int e = gw / H, h = gw % H;
    int s = src[e], d = dst[e];
    float alpha = ebuf[gw] / denom[d * H + h];
    float val = f[((size_t)s * H + h) * 64 + lane] * alpha;
    atomicAdd(&rst[((size_t)d * H + h) * 64 + lane], val);
}

// ---------------- epilogues ----------------
__global__ __launch_bounds__(256) void elu_ep(float* __restrict__ rst,
                                              const float* __restrict__ b, int total) {
    int i = blockIdx.x * blockDim.x + threadIdx.x;
    if (i >= total) return;
    float v = rst[i] + b[i & 511];
    rst[i] = v > 0.f ? v : (__expf(v) - 1.f);
}

__global__ __launch_bounds__(256) void out_ep(const float* __restrict__ rst,
                                              const float* __restrict__ b,
                                              float* __restrict__ out, int total) {
    int i = blockIdx.x * blockDim.x + threadIdx.x;
    if (i >= total) return;
    out[i] = rst[i] + b[i & 63];
}

extern "C" void kernel_launch(void* const* d_in, const int* in_sizes, int n_in,
                              void* d_out, int out_size, void* d_ws, size_t ws_size,
                              hipStream_t stream) {
    const float* x   = (const float*)d_in[0];
    const int*   src = (const int*)d_in[1];
    const int*   dst = (const int*)d_in[2];
    const float* W1  = (const float*)d_in[3];
    const float* al1 = (const float*)d_in[4];
    const float* ar1 = (const float*)d_in[5];
    const float* b1  = (const float*)d_in[6];
    const float* W2  = (const float*)d_in[7];
    const float* al2 = (const float*)d_in[8];
    const float* ar2 = (const float*)d_in[9];
    const float* b2  = (const float*)d_in[10];
    const float* W3  = (const float*)d_in[11];
    const float* al3 = (const float*)d_in[12];
    const float* ar3 = (const float*)d_in[13];
    const float* b3  = (const float*)d_in[14];
    const float* Wr3 = (const float*)d_in[15];
    float* out = (float*)d_out;

    // workspace layout (floats)
    float* ws = (float*)d_ws;
    const size_t NF = (size_t)N_NODES * 512;    // 25.6M
    float*    bufA  = ws;                        // f (per-layer features)
    float*    bufB  = bufA + NF;                 // rst / h (aggregation target)
    float*    el    = bufB + NF;                 // 400000
    float*    er    = el + (size_t)N_NODES * 8;  // 400000
    float*    ebuf  = er + (size_t)N_NODES * 8;  // 3.2M
    unsigned* m     = (unsigned*)(ebuf + (size_t)N_EDGES * 8);  // 400000
    float*    denom = (float*)(m + (size_t)N_NODES * 8);        // 400000
    float*    rst3  = denom + (size_t)N_NODES * 8;              // 3.2M

    const dim3 blk(256);
    const int E = N_EDGES, N = N_NODES;

    // ================= layer 1: in=256 -> 8 heads x 64 =================
    gemm64<<<dim3(512 / 64, (N + 63) / 64), blk, 0, stream>>>(x, W1, bufA, N, 512, 256);
    eler_k<8><<<(N * 8 + 3) / 4, blk, 0, stream>>>(bufA, al1, ar1, el, er, N);
    hipMemsetAsync(m, 0, (size_t)N * 8 * 4, stream);
    hipMemsetAsync(denom, 0, (size_t)N * 8 * 4, stream);
    edge_max_k<8><<<(E * 8 + 255) / 256, blk, 0, stream>>>(src, dst, el, er, ebuf, m, E);
    edge_expsum_k<8><<<(E * 8 + 255) / 256, blk, 0, stream>>>(dst, ebuf, m, denom, E);
    hipMemsetAsync(bufB, 0, NF * 4, stream);
    edge_agg_k<8><<<(E * 8 + 3) / 4, blk, 0, stream>>>(bufA, ebuf, denom, src, dst, bufB, E);
    elu_ep<<<((int)NF + 255) / 256, blk, 0, stream>>>(bufB, b1, (int)NF);
    // bufB now holds h1

    // ================= layer 2: in=512 -> 8 heads x 64, identity residual =================
    gemm64<<<dim3(512 / 64, (N + 63) / 64), blk, 0, stream>>>(bufB, W2, bufA, N, 512, 512);
    eler_k<8><<<(N * 8 + 3) / 4, blk, 0, stream>>>(bufA, al2, ar2, el, er, N);
    hipMemsetAsync(m, 0, (size_t)N * 8 * 4, stream);
    hipMemsetAsync(denom, 0, (size_t)N * 8 * 4, stream);
    edge_max_k<8><<<(E * 8 + 255) / 256, blk, 0, stream>>>(src, dst, el, er, ebuf, m, E);
    edge_expsum_k<8><<<(E * 8 + 255) / 256, blk, 0, stream>>>(dst, ebuf, m, denom, E);
    // residual: aggregate on top of h1 already in bufB (rst2 init = h1)
    edge_agg_k<8><<<(E * 8 + 3) / 4, blk, 0, stream>>>(bufA, ebuf, denom, src, dst, bufB, E);
    elu_ep<<<((int)NF + 255) / 256, blk, 0, stream>>>(bufB, b2, (int)NF);
    // bufB now holds h2

    // ================= layer 3: in=512 -> 1 head x 64, projected residual =================
    gemm64<<<dim3(1, (N + 63) / 64), blk, 0, stream>>>(bufB, W3, bufA, N, 64, 512);   // f3
    gemm64<<<dim3(1, (N + 63) / 64), blk, 0, stream>>>(bufB, Wr3, rst3, N, 64, 512);  // res3 = rst3 init
    eler_k<1><<<(N + 3) / 4, blk, 0, stream>>>(bufA, al3, ar3, el, er, N);
    hipMemsetAsync(m, 0, (size_t)N * 4, stream);
    hipMemsetAsync(denom, 0, (size_t)N * 4, stream);
    edge_max_k<1><<<(E + 255) / 256, blk, 0, stream>>>(src, dst, el, er, ebuf, m, E);
    edge_expsum_k<1><<<(E + 255) / 256, blk, 0, stream>>>(dst, ebuf, m, denom, E);
    edge_agg_k<1><<<(E + 3) / 4, blk, 0, stream>>>(bufA, ebuf, denom, src, dst, rst3, E);
    out_ep<<<(N * 64 + 255) / 256, blk, 0, stream>>>(rst3, b3, out, N * 64);
}

// Round 2
// 1134.028 us; speedup vs baseline: 2.1236x; 2.1236x over previous
//
#include <hip/hip_runtime.h>
#include <hip/hip_bf16.h>

#define N_NODES 50000
#define N_EDGES 400000
#define SCAN_B 256

// ---------------- GEMM: C[M,N] = A[M,K] @ B[K,N], row-major ----------------
__global__ __launch_bounds__(256) void gemm64(const float* __restrict__ A,
                                              const float* __restrict__ B,
                                              float* __restrict__ C,
                                              int M, int N, int K) {
    __shared__ float As[16][68];
    __shared__ float Bs[16][68];
    const int tid = threadIdx.x;
    const int bm = blockIdx.y * 64, bn = blockIdx.x * 64;
    const int tr = tid >> 4, tc = tid & 15;
    const int ar = tid >> 2, ac = (tid & 3) * 4;
    const int br = tid >> 4, bc = (tid & 15) * 4;
    float acc[4][4] = {};

    for (int k0 = 0; k0 < K; k0 += 16) {
        float4 av = make_float4(0.f, 0.f, 0.f, 0.f);
        if (bm + ar < M)
            av = *(const float4*)&A[(size_t)(bm + ar) * K + k0 + ac];
        As[ac + 0][ar] = av.x;
        As[ac + 1][ar] = av.y;
        As[ac + 2][ar] = av.z;
        As[ac + 3][ar] = av.w;
        float4 bv = *(const float4*)&B[(size_t)(k0 + br) * N + bn + bc];
        *(float4*)&Bs[br][bc] = bv;
        __syncthreads();
#pragma unroll
        for (int k = 0; k < 16; ++k) {
            float4 a = *(const float4*)&As[k][tr * 4];
            float4 b = *(const float4*)&Bs[k][tc * 4];
            float aa[4] = {a.x, a.y, a.z, a.w};
            float bb[4] = {b.x, b.y, b.z, b.w};
#pragma unroll
            for (int i = 0; i < 4; ++i)
#pragma unroll
                for (int j = 0; j < 4; ++j) acc[i][j] += aa[i] * bb[j];
        }
        __syncthreads();
    }
#pragma unroll
    for (int i = 0; i < 4; ++i) {
        int r = bm + tr * 4 + i;
        if (r < M) {
#pragma unroll
            for (int j = 0; j < 4; ++j)
                C[(size_t)r * N + bn + tc * 4 + j] = acc[i][j];
        }
    }
}

// ---------------- el/er: one wave per (node, head), D=64 lanes ----------------
template <int H>
__global__ __launch_bounds__(256) void eler_k(const float* __restrict__ f,
                                              const float* __restrict__ al,
                                              const float* __restrict__ ar,
                                              float* __restrict__ el,
                                              float* __restrict__ er, int N) {
    int gw = (blockIdx.x * blockDim.x + threadIdx.x) >> 6;
    int lane = threadIdx.x & 63;
    if (gw >= N * H) return;
    int h = gw % H;
    float v = f[(size_t)gw * 64 + lane];
    float pl = v * al[h * 64 + lane];
    float pr = v * ar[h * 64 + lane];
#pragma unroll
    for (int off = 32; off; off >>= 1) {
        pl += __shfl_xor(pl, off);
        pr += __shfl_xor(pr, off);
    }
    if (lane == 0) {
        el[gw] = pl;
        er[gw] = pr;
    }
}

// ---------------- CSR build ----------------
__global__ __launch_bounds__(256) void hist_k(const int* __restrict__ dst,
                                              int* __restrict__ deg, int E) {
    int i = blockIdx.x * blockDim.x + threadIdx.x;
    if (i < E) atomicAdd(&deg[dst[i]], 1);
}

__global__ __launch_bounds__(SCAN_B) void scan_blocks(const int* __restrict__ in,
                                                      int* __restrict__ out,
                                                      int* __restrict__ part, int n) {
    __shared__ int tmp[SCAN_B];
    int t = threadIdx.x, g = blockIdx.x * SCAN_B + t;
    int v = (g < n) ? in[g] : 0;
    tmp[t] = v;
    __syncthreads();
    for (int off = 1; off < SCAN_B; off <<= 1) {
        int add = (t >= off) ? tmp[t - off] : 0;
        __syncthreads();
        tmp[t] += add;
        __syncthreads();
    }
    if (g < n) out[g] = tmp[t] - v;  // exclusive
    if (t == SCAN_B - 1) part[blockIdx.x] = tmp[t];
}

__global__ __launch_bounds__(SCAN_B) void scan_part(int* __restrict__ part, int n) {
    __shared__ int tmp[SCAN_B];
    int t = threadIdx.x;
    int v = (t < n) ? part[t] : 0;
    tmp[t] = v;
    __syncthreads();
    for (int off = 1; off < SCAN_B; off <<= 1) {
        int add = (t >= off) ? tmp[t - off] : 0;
        __syncthreads();
        tmp[t] += add;
        __syncthreads();
    }
    if (t < n) part[t] = tmp[t] - v;  // exclusive
}

__global__ __launch_bounds__(256) void add_off(int* __restrict__ rowptr,
                                               int* __restrict__ cursor,
                                               const int* __restrict__ part,
                                               int n, int E) {
    int g = blockIdx.x * blockDim.x + threadIdx.x;
    if (g < n) {
        int v = rowptr[g] + part[g / SCAN_B];
        rowptr[g] = v;
        cursor[g] = v;
    }
    if (g == 0) rowptr[n] = E;
}

__global__ __launch_bounds__(256) void scatter_k(const int* __restrict__ src,
                                                 const int* __restrict__ dst,
                                                 int* __restrict__ cursor,
                                                 int* __restrict__ csr_src, int E) {
    int e = blockIdx.x * blockDim.x + threadIdx.x;
    if (e < E) {
        int p = atomicAdd(&cursor[dst[e]], 1);
        csr_src[p] = src[e];
    }
}

// ---------------- fused GAT aggregation: one wave per dst node, all H heads ----------------
template <int H, bool HAS_INIT, bool ELU>
__global__ __launch_bounds__(256) void gat_agg(const float* __restrict__ f,
                                               const float* __restrict__ el,
                                               const float* __restrict__ er,
                                               const int* __restrict__ rowptr,
                                               const int* __restrict__ csr_src,
                                               const float* __restrict__ init,
                                               const float* __restrict__ bias,
                                               float* __restrict__ outp, int N) {
    int w = (blockIdx.x * blockDim.x + threadIdx.x) >> 6;
    int lane = threadIdx.x & 63;
    if (w >= N) return;
    const int d = w;
    const int s0 = rowptr[d], s1 = rowptr[d + 1];
    const int hh = lane & (H - 1);
    const float erh = er[(size_t)d * H + hh];

    // phase 1: segment max (lanes split: head = lane%H, edge chunk = lane/H)
    float mx = -1e30f;
    for (int i = s0 + lane / H; i < s1; i += 64 / H) {
        float v = el[(size_t)csr_src[i] * H + hh] + erh;
        v = v > 0.f ? v : 0.2f * v;
        mx = fmaxf(mx, v);
    }
#pragma unroll
    for (int off = H; off < 64; off <<= 1) mx = fmaxf(mx, __shfl_xor(mx, off));

    // phase 2: sum of exp
    float sm = 0.f;
    for (int i = s0 + lane / H; i < s1; i += 64 / H) {
        float v = el[(size_t)csr_src[i] * H + hh] + erh;
        v = v > 0.f ? v : 0.2f * v;
        sm += __expf(v - mx);
    }
#pragma unroll
    for (int off = H; off < 64; off <<= 1) sm += __shfl_xor(sm, off);
    const float inv = sm > 0.f ? 1.0f / sm : 0.f;

    // phase 3: weighted gather (lane = feature dim). Lane h holds head-h m/inv.
    float acc[H] = {};
    for (int i = s0; i < s1; ++i) {
        int sn = csr_src[i];
        float v = el[(size_t)sn * H + hh] + erh;
        v = v > 0.f ? v : 0.2f * v;
        float a_mine = __expf(v - mx) * inv;  // alpha for head (lane%H)
        const float* fp = &f[(size_t)sn * H * 64 + lane];
#pragma unroll
        for (int h = 0; h < H; ++h) {
            float alpha = __shfl(a_mine, h);
            acc[h] += fp[h * 64] * alpha;
        }
    }

    // epilogue: residual init + bias + activation, single write
#pragma unroll
    for (int h = 0; h < H; ++h) {
        size_t o = ((size_t)d * H + h) * 64 + lane;
        float v = acc[h] + bias[h * 64 + lane];
        if (HAS_INIT) v += init[o];
        if (ELU) v = v > 0.f ? v : __expf(v) - 1.f;
        outp[o] = v;
    }
}

extern "C" void kernel_launch(void* const* d_in, const int* in_sizes, int n_in,
                              void* d_out, int out_size, void* d_ws, size_t ws_size,
                              hipStream_t stream) {
    const float* x   = (const float*)d_in[0];
    const int*   src = (const int*)d_in[1];
    const int*   dst = (const int*)d_in[2];
    const float* W1  = (const float*)d_in[3];
    const float* al1 = (const float*)d_in[4];
    const float* ar1 = (const float*)d_in[5];
    const float* b1  = (const float*)d_in[6];
    const float* W2  = (const float*)d_in[7];
    const float* al2 = (const float*)d_in[8];
    const float* ar2 = (const float*)d_in[9];
    const float* b2  = (const float*)d_in[10];
    const float* W3  = (const float*)d_in[11];
    const float* al3 = (const float*)d_in[12];
    const float* ar3 = (const float*)d_in[13];
    const float* b3  = (const float*)d_in[14];
    const float* Wr3 = (const float*)d_in[15];
    float* out = (float*)d_out;

    // workspace layout (floats)
    float* ws = (float*)d_ws;
    const size_t NF = (size_t)N_NODES * 512;
    float* bufA = ws;                               // features f (N*512)
    float* bufB = bufA + NF;                        // h / agg output (N*512)
    float* bufC = bufB + NF;                        // f3 (N*64)
    float* bufD = bufC + (size_t)N_NODES * 64;      // res3 (N*64)
    float* el   = bufD + (size_t)N_NODES * 64;      // N*8
    float* er   = el + (size_t)N_NODES * 8;         // N*8
    int* rowptr  = (int*)(er + (size_t)N_NODES * 8);  // N+1
    int* cursor  = rowptr + (N_NODES + 1);            // N
    int* part    = cursor + N_NODES;                  // 256
    int* csr_src = part + 256;                        // E

    const dim3 blk(256);
    const int E = N_EDGES, N = N_NODES;
    const int nb = (N + SCAN_B - 1) / SCAN_B;

    // ---------------- build CSR (per call; deterministic work) ----------------
    hipMemsetAsync(cursor, 0, (size_t)N * 4, stream);
    hist_k<<<(E + 255) / 256, blk, 0, stream>>>(dst, cursor, E);
    scan_blocks<<<nb, SCAN_B, 0, stream>>>(cursor, rowptr, part, N);
    scan_part<<<1, SCAN_B, 0, stream>>>(part, nb);
    add_off<<<nb, blk, 0, stream>>>(rowptr, cursor, part, N, E);
    scatter_k<<<(E + 255) / 256, blk, 0, stream>>>(src, dst, cursor, csr_src, E);

    // ================= layer 1: in=256 -> 8 heads x 64 =================
    gemm64<<<dim3(512 / 64, (N + 63) / 64), blk, 0, stream>>>(x, W1, bufA, N, 512, 256);
    eler_k<8><<<(N * 8 + 3) / 4, blk, 0, stream>>>(bufA, al1, ar1, el, er, N);
    gat_agg<8, false, true><<<(N + 3) / 4, blk, 0, stream>>>(
        bufA, el, er, rowptr, csr_src, nullptr, b1, bufB, N);

    // ================= layer 2: identity residual =================
    gemm64<<<dim3(512 / 64, (N + 63) / 64), blk, 0, stream>>>(bufB, W2, bufA, N, 512, 512);
    eler_k<8><<<(N * 8 + 3) / 4, blk, 0, stream>>>(bufA, al2, ar2, el, er, N);
    gat_agg<8, true, true><<<(N + 3) / 4, blk, 0, stream>>>(
        bufA, el, er, rowptr, csr_src, bufB, b2, bufB, N);

    // ================= layer 3: 1 head, projected residual =================
    gemm64<<<dim3(1, (N + 63) / 64), blk, 0, stream>>>(bufB, W3, bufC, N, 64, 512);
    gemm64<<<dim3(1, (N + 63) / 64), blk, 0, stream>>>(bufB, Wr3, bufD, N, 64, 512);
    eler_k<1><<<(N + 3) / 4, blk, 0, stream>>>(bufC, al3, ar3, el, er, N);
    gat_agg<1, true, false><<<(N + 3) / 4, blk, 0, stream>>>(
        bufC, el, er, rowptr, csr_src, bufD, b3, out, N);
}

// Round 3
// 511.136 us; speedup vs baseline: 4.7115x; 2.2186x over previous
//
#include <hip/hip_runtime.h>
#include <hip/hip_bf16.h>

#define N_NODES 50000
#define M_PAD 50048
#define N_EDGES 400000
#define SCAN_B 256

typedef __attribute__((ext_vector_type(8))) short short8;
typedef __attribute__((ext_vector_type(4))) float f32x4;

__device__ __forceinline__ float b2f(unsigned short u) {
    return __uint_as_float(((unsigned)u) << 16);
}
__device__ __forceinline__ unsigned short f2b(float f) {
    unsigned u = __float_as_uint(f);
    return (unsigned short)((u + 0x7fffu + ((u >> 16) & 1u)) >> 16);
}

__device__ __forceinline__ void gload_lds16(const void* g, void* l) {
    __builtin_amdgcn_global_load_lds(
        (const __attribute__((address_space(1))) unsigned int*)g,
        (__attribute__((address_space(3))) unsigned int*)l, 16, 0, 0);
}

// ---------------- conversions ----------------
__global__ __launch_bounds__(256) void conv_x4(const float* __restrict__ x,
                                               unsigned short* __restrict__ xb, int n4) {
    int i = blockIdx.x * blockDim.x + threadIdx.x;
    if (i >= n4) return;
    float4 v = *(const float4*)&x[(size_t)i * 4];
    unsigned short o[4] = {f2b(v.x), f2b(v.y), f2b(v.z), f2b(v.w)};
    *(ushort2*)&xb[(size_t)i * 4] = make_ushort2(o[0], o[1]);
    *(ushort2*)&xb[(size_t)i * 4 + 2] = make_ushort2(o[2], o[3]);
}

// W [K][N] fp32 -> Wt [N][K] bf16
__global__ __launch_bounds__(256) void conv_wt(const float* __restrict__ W,
                                               unsigned short* __restrict__ Wt,
                                               int K, int N) {
    int o = blockIdx.x * blockDim.x + threadIdx.x;
    if (o >= K * N) return;
    int n = o / K, k = o % K;
    Wt[o] = f2b(W[(size_t)k * N + n]);
}

// ---------------- bf16 MFMA GEMM: C[M][N] = A[M][K] @ Bt[N][K]^T ----------------
// 128x128 tile, BK=32, 256 threads (4 waves 2x2), mfma 16x16x32.
__global__ __launch_bounds__(256, 2) void gemm_mfma(const unsigned short* __restrict__ A,
                                                    const unsigned short* __restrict__ Bt,
                                                    unsigned short* __restrict__ C,
                                                    int M, int N, int K) {
    __shared__ unsigned short As[128 * 32];
    __shared__ unsigned short Bs[128 * 32];
    const int tid = threadIdx.x;
    const int w = tid >> 6, l = tid & 63;
    const int bm = blockIdx.y * 128, bn = blockIdx.x * 128;
    const int wr = w >> 1, wc = w & 1;
    const int rA = l >> 2;           // row within 16-row group
    const int kA = (l & 3) * 8;      // k element offset
    const int fr = l & 15, fq = l >> 4;
    f32x4 acc[4][4] = {};

    for (int k0 = 0; k0 < K; k0 += 32) {
#pragma unroll
        for (int j = 0; j < 2; ++j) {
            int row = w * 32 + j * 16 + rA;
            gload_lds16(&A[(size_t)(bm + row) * K + k0 + kA], &As[(w * 2 + j) * 512]);
            gload_lds16(&Bt[(size_t)(bn + row) * K + k0 + kA], &Bs[(w * 2 + j) * 512]);
        }
        __syncthreads();
        short8 a[4], b[4];
#pragma unroll
        for (int m = 0; m < 4; ++m)
            a[m] = *(const short8*)&As[(wr * 64 + m * 16 + fr) * 32 + fq * 8];
#pragma unroll
        for (int n = 0; n < 4; ++n)
            b[n] = *(const short8*)&Bs[(wc * 64 + n * 16 + fr) * 32 + fq * 8];
#pragma unroll
        for (int m = 0; m < 4; ++m)
#pragma unroll
            for (int n = 0; n < 4; ++n)
                acc[m][n] = __builtin_amdgcn_mfma_f32_16x16x32_bf16(a[m], b[n], acc[m][n], 0, 0, 0);
        __syncthreads();
    }

#pragma unroll
    for (int m = 0; m < 4; ++m) {
#pragma unroll
        for (int j = 0; j < 4; ++j) {
            int r = bm + wr * 64 + m * 16 + fq * 4 + j;
            if (r < M) {
#pragma unroll
                for (int n = 0; n < 4; ++n)
                    C[(size_t)r * N + bn + wc * 64 + n * 16 + fr] = f2b(acc[m][n][j]);
            }
        }
    }
}

// ---------------- el/er: one wave per (node, head) ----------------
template <int H>
__global__ __launch_bounds__(256) void eler_k(const unsigned short* __restrict__ f, int ldf,
                                              const float* __restrict__ al,
                                              const float* __restrict__ ar,
                                              float* __restrict__ el,
                                              float* __restrict__ er, int N) {
    int gw = (blockIdx.x * blockDim.x + threadIdx.x) >> 6;
    int lane = threadIdx.x & 63;
    if (gw >= N * H) return;
    int node = gw / H, h = gw % H;
    float v = b2f(f[(size_t)node * ldf + h * 64 + lane]);
    float pl = v * al[h * 64 + lane];
    float pr = v * ar[h * 64 + lane];
#pragma unroll
    for (int off = 32; off; off >>= 1) {
        pl += __shfl_xor(pl, off);
        pr += __shfl_xor(pr, off);
    }
    if (lane == 0) {
        el[gw] = pl;
        er[gw] = pr;
    }
}

// ---------------- CSR build ----------------
__global__ __launch_bounds__(256) void hist_k(const int* __restrict__ dst,
                                              int* __restrict__ deg, int E) {
    int i = blockIdx.x * blockDim.x + threadIdx.x;
    if (i < E) atomicAdd(&deg[dst[i]], 1);
}

__global__ __launch_bounds__(SCAN_B) void scan_blocks(const int* __restrict__ in,
                                                      int* __restrict__ out,
                                                      int* __restrict__ part, int n) {
    __shared__ int tmp[SCAN_B];
    int t = threadIdx.x, g = blockIdx.x * SCAN_B + t;
    int v = (g < n) ? in[g] : 0;
    tmp[t] = v;
    __syncthreads();
    for (int off = 1; off < SCAN_B; off <<= 1) {
        int add = (t >= off) ? tmp[t - off] : 0;
        __syncthreads();
        tmp[t] += add;
        __syncthreads();
    }
    if (g < n) out[g] = tmp[t] - v;
    if (t == SCAN_B - 1) part[blockIdx.x] = tmp[t];
}

__global__ __launch_bounds__(SCAN_B) void scan_part(int* __restrict__ part, int n) {
    __shared__ int tmp[SCAN_B];
    int t = threadIdx.x;
    int v = (t < n) ? part[t] : 0;
    tmp[t] = v;
    __syncthreads();
    for (int off = 1; off < SCAN_B; off <<= 1) {
        int add = (t >= off) ? tmp[t - off] : 0;
        __syncthreads();
        tmp[t] += add;
        __syncthreads();
    }
    if (t < n) part[t] = tmp[t] - v;
}

__global__ __launch_bounds__(256) void add_off(int* __restrict__ rowptr,
                                               int* __restrict__ cursor,
                                               const int* __restrict__ part,
                                               int n, int E) {
    int g = blockIdx.x * blockDim.x + threadIdx.x;
    if (g < n) {
        int v = rowptr[g] + part[g / SCAN_B];
        rowptr[g] = v;
        cursor[g] = v;
    }
    if (g == 0) rowptr[n] = E;
}

__global__ __launch_bounds__(256) void scatter_k(const int* __restrict__ src,
                                                 const int* __restrict__ dst,
                                                 int* __restrict__ cursor,
                                                 int* __restrict__ csr_src, int E) {
    int e = blockIdx.x * blockDim.x + threadIdx.x;
    if (e < E) {
        int p = atomicAdd(&cursor[dst[e]], 1);
        csr_src[p] = src[e];
    }
}

// ---------------- fused GAT aggregation: one wave per dst node ----------------
template <int H, bool HAS_INIT, bool ELU, bool OUTF32>
__global__ __launch_bounds__(256) void gat_agg(const unsigned short* __restrict__ f, int ldf,
                                               const float* __restrict__ el,
                                               const float* __restrict__ er,
                                               const int* __restrict__ rowptr,
                                               const int* __restrict__ csr_src,
                                               const unsigned short* __restrict__ init, int ldinit,
                                               const float* __restrict__ bias,
                                               float* __restrict__ outf,
                                               unsigned short* __restrict__ outb, int N) {
    int w = (blockIdx.x * blockDim.x + threadIdx.x) >> 6;
    int lane = threadIdx.x & 63;
    if (w >= N) return;
    const int d = w;
    const int s0 = rowptr[d], s1 = rowptr[d + 1];
    const int hh = lane & (H - 1);
    const float erh = er[(size_t)d * H + hh];

    float mx = -1e30f;
    for (int i = s0 + lane / H; i < s1; i += 64 / H) {
        float v = el[(size_t)csr_src[i] * H + hh] + erh;
        v = v > 0.f ? v : 0.2f * v;
        mx = fmaxf(mx, v);
    }
#pragma unroll
    for (int off = H; off < 64; off <<= 1) mx = fmaxf(mx, __shfl_xor(mx, off));

    float sm = 0.f;
    for (int i = s0 + lane / H; i < s1; i += 64 / H) {
        float v = el[(size_t)csr_src[i] * H + hh] + erh;
        v = v > 0.f ? v : 0.2f * v;
        sm += __expf(v - mx);
    }
#pragma unroll
    for (int off = H; off < 64; off <<= 1) sm += __shfl_xor(sm, off);
    const float inv = sm > 0.f ? 1.0f / sm : 0.f;

    float acc[H] = {};
    for (int i = s0; i < s1; ++i) {
        int sn = csr_src[i];
        float v = el[(size_t)sn * H + hh] + erh;
        v = v > 0.f ? v : 0.2f * v;
        float a_mine = __expf(v - mx) * inv;
        const unsigned short* fp = &f[(size_t)sn * ldf + lane];
#pragma unroll
        for (int h = 0; h < H; ++h) {
            float alpha = __shfl(a_mine, h);
            acc[h] += b2f(fp[h * 64]) * alpha;
        }
    }

#pragma unroll
    for (int h = 0; h < H; ++h) {
        size_t o = ((size_t)d * H + h) * 64 + lane;
        float v = acc[h] + bias[h * 64 + lane];
        if (HAS_INIT) v += b2f(init[(size_t)d * ldinit + h * 64 + lane]);
        if (ELU) v = v > 0.f ? v : __expf(v) - 1.f;
        if (OUTF32) outf[o] = v; else outb[o] = f2b(v);
    }
}

extern "C" void kernel_launch(void* const* d_in, const int* in_sizes, int n_in,
                              void* d_out, int out_size, void* d_ws, size_t ws_size,
                              hipStream_t stream) {
    const float* x   = (const float*)d_in[0];
    const int*   src = (const int*)d_in[1];
    const int*   dst = (const int*)d_in[2];
    const float* W1  = (const float*)d_in[3];
    const float* al1 = (const float*)d_in[4];
    const float* ar1 = (const float*)d_in[5];
    const float* b1  = (const float*)d_in[6];
    const float* W2  = (const float*)d_in[7];
    const float* al2 = (const float*)d_in[8];
    const float* ar2 = (const float*)d_in[9];
    const float* b2  = (const float*)d_in[10];
    const float* W3  = (const float*)d_in[11];
    const float* al3 = (const float*)d_in[12];
    const float* ar3 = (const float*)d_in[13];
    const float* b3  = (const float*)d_in[14];
    const float* Wr3 = (const float*)d_in[15];
    float* out = (float*)d_out;

    // workspace layout
    unsigned short* xb   = (unsigned short*)d_ws;               // [M_PAD][256]
    unsigned short* fb   = xb + (size_t)M_PAD * 256;            // [M_PAD][512]
    unsigned short* h1b  = fb + (size_t)M_PAD * 512;            // [M_PAD][512]
    unsigned short* h2b  = h1b + (size_t)M_PAD * 512;           // [M_PAD][512]
    unsigned short* f3r  = h2b + (size_t)M_PAD * 512;           // [M_PAD][128]
    unsigned short* Wt1  = f3r + (size_t)M_PAD * 128;           // [512][256]
    unsigned short* Wt2  = Wt1 + 512 * 256;                     // [512][512]
    unsigned short* Wt3  = Wt2 + 512 * 512;                     // [128][512]
    float* el = (float*)(Wt3 + 128 * 512);                      // N*8
    float* er = el + (size_t)N_NODES * 8;                       // N*8
    int* rowptr  = (int*)(er + (size_t)N_NODES * 8);            // N+1
    int* cursor  = rowptr + (N_NODES + 1);
    int* part    = cursor + N_NODES;
    int* csr_src = part + 256;                                  // E

    const dim3 blk(256);
    const int E = N_EDGES, N = N_NODES;
    const int nb = (N + SCAN_B - 1) / SCAN_B;
    const int gy = (N + 127) / 128;  // 391

    // conversions
    conv_x4<<<(N * 64 + 255) / 256, blk, 0, stream>>>(x, xb, N * 64);  // N*256/4 threads
    conv_wt<<<(512 * 256 + 255) / 256, blk, 0, stream>>>(W1, Wt1, 256, 512);
    conv_wt<<<(512 * 512 + 255) / 256, blk, 0, stream>>>(W2, Wt2, 512, 512);
    conv_wt<<<(64 * 512 + 255) / 256, blk, 0, stream>>>(W3, Wt3, 512, 64);
    conv_wt<<<(64 * 512 + 255) / 256, blk, 0, stream>>>(Wr3, Wt3 + 64 * 512, 512, 64);

    // CSR build
    hipMemsetAsync(cursor, 0, (size_t)N * 4, stream);
    hist_k<<<(E + 255) / 256, blk, 0, stream>>>(dst, cursor, E);
    scan_blocks<<<nb, SCAN_B, 0, stream>>>(cursor, rowptr, part, N);
    scan_part<<<1, SCAN_B, 0, stream>>>(part, nb);
    add_off<<<nb, blk, 0, stream>>>(rowptr, cursor, part, N, E);
    scatter_k<<<(E + 255) / 256, blk, 0, stream>>>(src, dst, cursor, csr_src, E);

    // ================= layer 1 =================
    gemm_mfma<<<dim3(4, gy), blk, 0, stream>>>(xb, Wt1, fb, N, 512, 256);
    eler_k<8><<<(N * 8 + 3) / 4, blk, 0, stream>>>(fb, 512, al1, ar1, el, er, N);
    gat_agg<8, false, true, false><<<(N + 3) / 4, blk, 0, stream>>>(
        fb, 512, el, er, rowptr, csr_src, nullptr, 0, b1, nullptr, h1b, N);

    // ================= layer 2 (identity residual = h1) =================
    gemm_mfma<<<dim3(4, gy), blk, 0, stream>>>(h1b, Wt2, fb, N, 512, 512);
    eler_k<8><<<(N * 8 + 3) / 4, blk, 0, stream>>>(fb, 512, al2, ar2, el, er, N);
    gat_agg<8, true, true, false><<<(N + 3) / 4, blk, 0, stream>>>(
        fb, 512, el, er, rowptr, csr_src, h1b, 512, b2, nullptr, h2b, N);

    // ================= layer 3 (1 head, projected residual) =================
    gemm_mfma<<<dim3(1, gy), blk, 0, stream>>>(h2b, Wt3, f3r, N, 128, 512);
    eler_k<1><<<(N + 3) / 4, blk, 0, stream>>>(f3r, 128, al3, ar3, el, er, N);
    gat_agg<1, true, false, true><<<(N + 3) / 4, blk, 0, stream>>>(
        f3r, 128, el, er, rowptr, csr_src, f3r + 64, 128, b3, out, nullptr, N);
}

// Round 4
// 395.233 us; speedup vs baseline: 6.0931x; 1.2933x over previous
//
#include <hip/hip_runtime.h>
#include <hip/hip_bf16.h>

#define N_NODES 50000
#define M_PAD 50048
#define N_EDGES 400000
#define SCAN_B 256

typedef __attribute__((ext_vector_type(8))) short short8;
typedef __attribute__((ext_vector_type(4))) float f32x4;

__device__ __forceinline__ float b2f(unsigned short u) {
    return __uint_as_float(((unsigned)u) << 16);
}
__device__ __forceinline__ unsigned short f2b(float f) {
    unsigned u = __float_as_uint(f);
    return (unsigned short)((u + 0x7fffu + ((u >> 16) & 1u)) >> 16);
}
__device__ __forceinline__ float blo(unsigned u) { return __uint_as_float(u << 16); }
__device__ __forceinline__ float bhi(unsigned u) { return __uint_as_float(u & 0xffff0000u); }

__device__ __forceinline__ void gload_lds16(const void* g, void* l) {
    __builtin_amdgcn_global_load_lds(
        (const __attribute__((address_space(1))) unsigned int*)g,
        (__attribute__((address_space(3))) unsigned int*)l, 16, 0, 0);
}

// ---------------- conversions ----------------
__global__ __launch_bounds__(256) void conv_x4(const float* __restrict__ x,
                                               unsigned short* __restrict__ xb, int n4) {
    int i = blockIdx.x * blockDim.x + threadIdx.x;
    if (i >= n4) return;
    float4 v = *(const float4*)&x[(size_t)i * 4];
    unsigned short o[4] = {f2b(v.x), f2b(v.y), f2b(v.z), f2b(v.w)};
    *(ushort2*)&xb[(size_t)i * 4] = make_ushort2(o[0], o[1]);
    *(ushort2*)&xb[(size_t)i * 4 + 2] = make_ushort2(o[2], o[3]);
}

// W [K][N] fp32 -> Wt [N][K] bf16
__global__ __launch_bounds__(256) void conv_wt(const float* __restrict__ W,
                                               unsigned short* __restrict__ Wt,
                                               int K, int N) {
    int o = blockIdx.x * blockDim.x + threadIdx.x;
    if (o >= K * N) return;
    int n = o / K, k = o % K;
    Wt[o] = f2b(W[(size_t)k * N + n]);
}

// ---------------- bf16 MFMA GEMM: C[M][N] = A[M][K] @ Bt[N][K]^T ----------------
__global__ __launch_bounds__(256, 2) void gemm_mfma(const unsigned short* __restrict__ A,
                                                    const unsigned short* __restrict__ Bt,
                                                    unsigned short* __restrict__ C,
                                                    int M, int N, int K) {
    __shared__ unsigned short As[128 * 32];
    __shared__ unsigned short Bs[128 * 32];
    const int tid = threadIdx.x;
    const int w = tid >> 6, l = tid & 63;
    const int bm = blockIdx.y * 128, bn = blockIdx.x * 128;
    const int wr = w >> 1, wc = w & 1;
    const int rA = l >> 2;
    const int kA = (l & 3) * 8;
    const int fr = l & 15, fq = l >> 4;
    f32x4 acc[4][4] = {};

    for (int k0 = 0; k0 < K; k0 += 32) {
#pragma unroll
        for (int j = 0; j < 2; ++j) {
            int row = w * 32 + j * 16 + rA;
            gload_lds16(&A[(size_t)(bm + row) * K + k0 + kA], &As[(w * 2 + j) * 512]);
            gload_lds16(&Bt[(size_t)(bn + row) * K + k0 + kA], &Bs[(w * 2 + j) * 512]);
        }
        __syncthreads();
        short8 a[4], b[4];
#pragma unroll
        for (int m = 0; m < 4; ++m)
            a[m] = *(const short8*)&As[(wr * 64 + m * 16 + fr) * 32 + fq * 8];
#pragma unroll
        for (int n = 0; n < 4; ++n)
            b[n] = *(const short8*)&Bs[(wc * 64 + n * 16 + fr) * 32 + fq * 8];
#pragma unroll
        for (int m = 0; m < 4; ++m)
#pragma unroll
            for (int n = 0; n < 4; ++n)
                acc[m][n] = __builtin_amdgcn_mfma_f32_16x16x32_bf16(a[m], b[n], acc[m][n], 0, 0, 0);
        __syncthreads();
    }

#pragma unroll
    for (int m = 0; m < 4; ++m) {
#pragma unroll
        for (int j = 0; j < 4; ++j) {
            int r = bm + wr * 64 + m * 16 + fq * 4 + j;
            if (r < M) {
#pragma unroll
                for (int n = 0; n < 4; ++n)
                    C[(size_t)r * N + bn + wc * 64 + n * 16 + fr] = f2b(acc[m][n][j]);
            }
        }
    }
}

// ---------------- el/er for H=8: one wave per node, uint4 loads ----------------
__global__ __launch_bounds__(256) void eler8_k(const unsigned short* __restrict__ f,
                                               const float* __restrict__ al,
                                               const float* __restrict__ ar,
                                               float* __restrict__ el,
                                               float* __restrict__ er, int N) {
    int w = (blockIdx.x * blockDim.x + threadIdx.x) >> 6;
    int lane = threadIdx.x & 63;
    if (w >= N) return;
    const int h = lane >> 3, sl = (lane & 7) * 8;
    uint4 pk = *(const uint4*)&f[(size_t)w * 512 + h * 64 + sl];
    float4 a0 = *(const float4*)&al[h * 64 + sl];
    float4 a1 = *(const float4*)&al[h * 64 + sl + 4];
    float4 r0 = *(const float4*)&ar[h * 64 + sl];
    float4 r1 = *(const float4*)&ar[h * 64 + sl + 4];
    float x0 = blo(pk.x), x1 = bhi(pk.x), x2 = blo(pk.y), x3 = bhi(pk.y);
    float x4 = blo(pk.z), x5 = bhi(pk.z), x6 = blo(pk.w), x7 = bhi(pk.w);
    float pl = x0 * a0.x + x1 * a0.y + x2 * a0.z + x3 * a0.w +
               x4 * a1.x + x5 * a1.y + x6 * a1.z + x7 * a1.w;
    float pr = x0 * r0.x + x1 * r0.y + x2 * r0.z + x3 * r0.w +
               x4 * r1.x + x5 * r1.y + x6 * r1.z + x7 * r1.w;
#pragma unroll
    for (int off = 1; off < 8; off <<= 1) {
        pl += __shfl_xor(pl, off);
        pr += __shfl_xor(pr, off);
    }
    if ((lane & 7) == 0) {
        el[(size_t)w * 8 + h] = pl;
        er[(size_t)w * 8 + h] = pr;
    }
}

// ---------------- el/er for H=1 ----------------
__global__ __launch_bounds__(256) void eler1_k(const unsigned short* __restrict__ f, int ldf,
                                               const float* __restrict__ al,
                                               const float* __restrict__ ar,
                                               float* __restrict__ el,
                                               float* __restrict__ er, int N) {
    int gw = (blockIdx.x * blockDim.x + threadIdx.x) >> 6;
    int lane = threadIdx.x & 63;
    if (gw >= N) return;
    float v = b2f(f[(size_t)gw * ldf + lane]);
    float pl = v * al[lane];
    float pr = v * ar[lane];
#pragma unroll
    for (int off = 32; off; off >>= 1) {
        pl += __shfl_xor(pl, off);
        pr += __shfl_xor(pr, off);
    }
    if (lane == 0) {
        el[gw] = pl;
        er[gw] = pr;
    }
}

// ---------------- CSR build ----------------
__global__ __launch_bounds__(256) void hist_k(const int* __restrict__ dst,
                                              int* __restrict__ deg, int E) {
    int i = blockIdx.x * blockDim.x + threadIdx.x;
    if (i < E) atomicAdd(&deg[dst[i]], 1);
}

__global__ __launch_bounds__(SCAN_B) void scan_blocks(const int* __restrict__ in,
                                                      int* __restrict__ out,
                                                      int* __restrict__ part, int n) {
    __shared__ int tmp[SCAN_B];
    int t = threadIdx.x, g = blockIdx.x * SCAN_B + t;
    int v = (g < n) ? in[g] : 0;
    tmp[t] = v;
    __syncthreads();
    for (int off = 1; off < SCAN_B; off <<= 1) {
        int add = (t >= off) ? tmp[t - off] : 0;
        __syncthreads();
        tmp[t] += add;
        __syncthreads();
    }
    if (g < n) out[g] = tmp[t] - v;
    if (t == SCAN_B - 1) part[blockIdx.x] = tmp[t];
}

__global__ __launch_bounds__(SCAN_B) void scan_part(int* __restrict__ part, int n) {
    __shared__ int tmp[SCAN_B];
    int t = threadIdx.x;
    int v = (t < n) ? part[t] : 0;
    tmp[t] = v;
    __syncthreads();
    for (int off = 1; off < SCAN_B; off <<= 1) {
        int add = (t >= off) ? tmp[t - off] : 0;
        __syncthreads();
        tmp[t] += add;
        __syncthreads();
    }
    if (t < n) part[t] = tmp[t] - v;
}

__global__ __launch_bounds__(256) void add_off(int* __restrict__ rowptr,
                                               int* __restrict__ cursor,
                                               const int* __restrict__ part,
                                               int n, int E) {
    int g = blockIdx.x * blockDim.x + threadIdx.x;
    if (g < n) {
        int v = rowptr[g] + part[g / SCAN_B];
        rowptr[g] = v;
        cursor[g] = v;
    }
    if (g == 0) rowptr[n] = E;
}

__global__ __launch_bounds__(256) void scatter_k(const int* __restrict__ src,
                                                 const int* __restrict__ dst,
                                                 int* __restrict__ cursor,
                                                 int* __restrict__ csr_src, int E) {
    int e = blockIdx.x * blockDim.x + threadIdx.x;
    if (e < E) {
        int p = atomicAdd(&cursor[dst[e]], 1);
        csr_src[p] = src[e];
    }
}

// ---------------- fused GAT aggregation H=8: one wave per dst, uint4 gather ----------------
template <bool HAS_INIT>
__global__ __launch_bounds__(256) void gat_agg8(const unsigned short* __restrict__ f,
                                                const float* __restrict__ el,
                                                const float* __restrict__ er,
                                                const int* __restrict__ rowptr,
                                                const int* __restrict__ csr_src,
                                                const unsigned short* __restrict__ init,
                                                const float* __restrict__ bias,
                                                unsigned short* __restrict__ outb, int N) {
    int w = (blockIdx.x * blockDim.x + threadIdx.x) >> 6;
    int lane = threadIdx.x & 63;
    if (w >= N) return;
    const int d = w;
    const int s0 = rowptr[d], s1 = rowptr[d + 1];
    const int hh = lane & 7;
    const float erh = er[(size_t)d * 8 + hh];

    // phase 1: per-head max (lanes: edge_sub = lane>>3, head = lane&7)
    float mx = -1e30f;
    for (int i = s0 + (lane >> 3); i < s1; i += 8) {
        float v = el[(size_t)csr_src[i] * 8 + hh] + erh;
        v = v > 0.f ? v : 0.2f * v;
        mx = fmaxf(mx, v);
    }
#pragma unroll
    for (int off = 8; off < 64; off <<= 1) mx = fmaxf(mx, __shfl_xor(mx, off));

    // phase 2: per-head sum of exp
    float sm = 0.f;
    for (int i = s0 + (lane >> 3); i < s1; i += 8) {
        float v = el[(size_t)csr_src[i] * 8 + hh] + erh;
        v = v > 0.f ? v : 0.2f * v;
        sm += __expf(v - mx);
    }
#pragma unroll
    for (int off = 8; off < 64; off <<= 1) sm += __shfl_xor(sm, off);
    const float inv = sm > 0.f ? 1.0f / sm : 0.f;

    // phase 3: lane = (head = lane>>3, dim slice = (lane&7)*8), 16B gather per edge
    const int myhead = lane >> 3;
    const int sl = (lane & 7) * 8;
    float acc[8] = {};
    for (int i = s0; i < s1; ++i) {
        int sn = csr_src[i];
        float v = el[(size_t)sn * 8 + hh] + erh;
        v = v > 0.f ? v : 0.2f * v;
        float am = __expf(v - mx) * inv;        // alpha for head (lane&7)
        float alpha = __shfl(am, myhead);       // alpha for my head
        uint4 pk = *(const uint4*)&f[(size_t)sn * 512 + myhead * 64 + sl];
        acc[0] += blo(pk.x) * alpha;
        acc[1] += bhi(pk.x) * alpha;
        acc[2] += blo(pk.y) * alpha;
        acc[3] += bhi(pk.y) * alpha;
        acc[4] += blo(pk.z) * alpha;
        acc[5] += bhi(pk.z) * alpha;
        acc[6] += blo(pk.w) * alpha;
        acc[7] += bhi(pk.w) * alpha;
    }

    // epilogue: bias + (init) + ELU, pack bf16, one 16B store
    float4 b0 = *(const float4*)&bias[myhead * 64 + sl];
    float4 b1 = *(const float4*)&bias[myhead * 64 + sl + 4];
    float bb[8] = {b0.x, b0.y, b0.z, b0.w, b1.x, b1.y, b1.z, b1.w};
    if (HAS_INIT) {
        uint4 iv = *(const uint4*)&init[(size_t)d * 512 + myhead * 64 + sl];
        acc[0] += blo(iv.x); acc[1] += bhi(iv.x);
        acc[2] += blo(iv.y); acc[3] += bhi(iv.y);
        acc[4] += blo(iv.z); acc[5] += bhi(iv.z);
        acc[6] += blo(iv.w); acc[7] += bhi(iv.w);
    }
    unsigned short ob[8];
#pragma unroll
    for (int j = 0; j < 8; ++j) {
        float v = acc[j] + bb[j];
        v = v > 0.f ? v : __expf(v) - 1.f;
        ob[j] = f2b(v);
    }
    uint4 ov;
    ov.x = (unsigned)ob[0] | ((unsigned)ob[1] << 16);
    ov.y = (unsigned)ob[2] | ((unsigned)ob[3] << 16);
    ov.z = (unsigned)ob[4] | ((unsigned)ob[5] << 16);
    ov.w = (unsigned)ob[6] | ((unsigned)ob[7] << 16);
    *(uint4*)&outb[((size_t)d * 8 + myhead) * 64 + sl] = ov;
}

// ---------------- fused GAT aggregation H=1 (layer 3): 8 edges/wave ----------------
__global__ __launch_bounds__(256) void gat_agg1(const unsigned short* __restrict__ f, // [*,128]
                                                const float* __restrict__ el,
                                                const float* __restrict__ er,
                                                const int* __restrict__ rowptr,
                                                const int* __restrict__ csr_src,
                                                const float* __restrict__ bias,
                                                float* __restrict__ outf, int N) {
    int w = (blockIdx.x * blockDim.x + threadIdx.x) >> 6;
    int lane = threadIdx.x & 63;
    if (w >= N) return;
    const int d = w;
    const int s0 = rowptr[d], s1 = rowptr[d + 1];
    const float erh = er[d];

    float mx = -1e30f;
    for (int i = s0 + lane; i < s1; i += 64) {
        float v = el[csr_src[i]] + erh;
        v = v > 0.f ? v : 0.2f * v;
        mx = fmaxf(mx, v);
    }
#pragma unroll
    for (int off = 1; off < 64; off <<= 1) mx = fmaxf(mx, __shfl_xor(mx, off));

    float sm = 0.f;
    for (int i = s0 + lane; i < s1; i += 64) {
        float v = el[csr_src[i]] + erh;
        v = v > 0.f ? v : 0.2f * v;
        sm += __expf(v - mx);
    }
#pragma unroll
    for (int off = 1; off < 64; off <<= 1) sm += __shfl_xor(sm, off);
    const float inv = sm > 0.f ? 1.0f / sm : 0.f;

    const int esub = lane >> 3, sl = (lane & 7) * 8;
    float acc[8] = {};
    for (int i0 = s0; i0 < s1; i0 += 8) {
        int i = i0 + esub;
        bool valid = i < s1;
        int sn = csr_src[valid ? i : s0];
        float v = el[sn] + erh;
        v = v > 0.f ? v : 0.2f * v;
        float alpha = valid ? __expf(v - mx) * inv : 0.f;
        uint4 pk = *(const uint4*)&f[(size_t)sn * 128 + sl];
        acc[0] += blo(pk.x) * alpha;
        acc[1] += bhi(pk.x) * alpha;
        acc[2] += blo(pk.y) * alpha;
        acc[3] += bhi(pk.y) * alpha;
        acc[4] += blo(pk.z) * alpha;
        acc[5] += bhi(pk.z) * alpha;
        acc[6] += blo(pk.w) * alpha;
        acc[7] += bhi(pk.w) * alpha;
    }
#pragma unroll
    for (int off = 8; off < 64; off <<= 1)
#pragma unroll
        for (int j = 0; j < 8; ++j) acc[j] += __shfl_xor(acc[j], off);

    if (esub == 0) {
        // residual res3 lives at f[...,64..127]
        uint4 rv = *(const uint4*)&f[(size_t)d * 128 + 64 + sl];
        float rr[8] = {blo(rv.x), bhi(rv.x), blo(rv.y), bhi(rv.y),
                       blo(rv.z), bhi(rv.z), blo(rv.w), bhi(rv.w)};
#pragma unroll
        for (int j = 0; j < 8; ++j)
            outf[(size_t)d * 64 + sl + j] = acc[j] + bias[sl + j] + rr[j];
    }
}

extern "C" void kernel_launch(void* const* d_in, const int* in_sizes, int n_in,
                              void* d_out, int out_size, void* d_ws, size_t ws_size,
                              hipStream_t stream) {
    const float* x   = (const float*)d_in[0];
    const int*   src = (const int*)d_in[1];
    const int*   dst = (const int*)d_in[2];
    const float* W1  = (const float*)d_in[3];
    const float* al1 = (const float*)d_in[4];
    const float* ar1 = (const float*)d_in[5];
    const float* b1  = (const float*)d_in[6];
    const float* W2  = (const float*)d_in[7];
    const float* al2 = (const float*)d_in[8];
    const float* ar2 = (const float*)d_in[9];
    const float* b2  = (const float*)d_in[10];
    const float* W3  = (const float*)d_in[11];
    const float* al3 = (const float*)d_in[12];
    const float* ar3 = (const float*)d_in[13];
    const float* b3  = (const float*)d_in[14];
    const float* Wr3 = (const float*)d_in[15];
    float* out = (float*)d_out;

    unsigned short* xb   = (unsigned short*)d_ws;               // [M_PAD][256]
    unsigned short* fb   = xb + (size_t)M_PAD * 256;            // [M_PAD][512]
    unsigned short* h1b  = fb + (size_t)M_PAD * 512;            // [M_PAD][512]
    unsigned short* h2b  = h1b + (size_t)M_PAD * 512;           // [M_PAD][512]
    unsigned short* f3r  = h2b + (size_t)M_PAD * 512;           // [M_PAD][128]
    unsigned short* Wt1  = f3r + (size_t)M_PAD * 128;           // [512][256]
    unsigned short* Wt2  = Wt1 + 512 * 256;                     // [512][512]
    unsigned short* Wt3  = Wt2 + 512 * 512;                     // [128][512]
    float* el = (float*)(Wt3 + 128 * 512);                      // N*8
    float* er = el + (size_t)N_NODES * 8;                       // N*8
    int* rowptr  = (int*)(er + (size_t)N_NODES * 8);            // N+1
    int* cursor  = rowptr + (N_NODES + 1);
    int* part    = cursor + N_NODES;
    int* csr_src = part + 256;                                  // E

    const dim3 blk(256);
    const int E = N_EDGES, N = N_NODES;
    const int nb = (N + SCAN_B - 1) / SCAN_B;
    const int gy = (N + 127) / 128;

    conv_x4<<<(N * 64 + 255) / 256, blk, 0, stream>>>(x, xb, N * 64);
    conv_wt<<<(512 * 256 + 255) / 256, blk, 0, stream>>>(W1, Wt1, 256, 512);
    conv_wt<<<(512 * 512 + 255) / 256, blk, 0, stream>>>(W2, Wt2, 512, 512);
    conv_wt<<<(64 * 512 + 255) / 256, blk, 0, stream>>>(W3, Wt3, 512, 64);
    conv_wt<<<(64 * 512 + 255) / 256, blk, 0, stream>>>(Wr3, Wt3 + 64 * 512, 512, 64);

    hipMemsetAsync(cursor, 0, (size_t)N * 4, stream);
    hist_k<<<(E + 255) / 256, blk, 0, stream>>>(dst, cursor, E);
    scan_blocks<<<nb, SCAN_B, 0, stream>>>(cursor, rowptr, part, N);
    scan_part<<<1, SCAN_B, 0, stream>>>(part, nb);
    add_off<<<nb, blk, 0, stream>>>(rowptr, cursor, part, N, E);
    scatter_k<<<(E + 255) / 256, blk, 0, stream>>>(src, dst, cursor, csr_src, E);

    // ================= layer 1 =================
    gemm_mfma<<<dim3(4, gy), blk, 0, stream>>>(xb, Wt1, fb, N, 512, 256);
    eler8_k<<<(N + 3) / 4, blk, 0, stream>>>(fb, al1, ar1, el, er, N);
    gat_agg8<false><<<(N + 3) / 4, blk, 0, stream>>>(
        fb, el, er, rowptr, csr_src, nullptr, b1, h1b, N);

    // ================= layer 2 (identity residual = h1) =================
    gemm_mfma<<<dim3(4, gy), blk, 0, stream>>>(h1b, Wt2, fb, N, 512, 512);
    eler8_k<<<(N + 3) / 4, blk, 0, stream>>>(fb, al2, ar2, el, er, N);
    gat_agg8<true><<<(N + 3) / 4, blk, 0, stream>>>(
        fb, el, er, rowptr, csr_src, h1b, b2, h2b, N);

    // ================= layer 3 (1 head, projected residual) =================
    gemm_mfma<<<dim3(1, gy), blk, 0, stream>>>(h2b, Wt3, f3r, N, 128, 512);
    eler1_k<<<(N + 3) / 4, blk, 0, stream>>>(f3r, 128, al3, ar3, el, er, N);
    gat_agg1<<<(N + 3) / 4, blk, 0, stream>>>(
        f3r, el, er, rowptr, csr_src, b3, out, N);
}

// Round 5
// 369.613 us; speedup vs baseline: 6.5155x; 1.0693x over previous
//
#include <hip/hip_runtime.h>
#include <hip/hip_bf16.h>

#define N_NODES 50000
#define M_PAD 50048
#define N_EDGES 400000
#define SCAN_B 256

typedef __attribute__((ext_vector_type(8))) short short8;
typedef __attribute__((ext_vector_type(4))) float f32x4;

__device__ __forceinline__ float b2f(unsigned short u) {
    return __uint_as_float(((unsigned)u) << 16);
}
__device__ __forceinline__ unsigned short f2b(float f) {
    unsigned u = __float_as_uint(f);
    return (unsigned short)((u + 0x7fffu + ((u >> 16) & 1u)) >> 16);
}
__device__ __forceinline__ float blo(unsigned u) { return __uint_as_float(u << 16); }
__device__ __forceinline__ float bhi(unsigned u) { return __uint_as_float(u & 0xffff0000u); }

__device__ __forceinline__ void gload_lds16(const void* g, void* l) {
    __builtin_amdgcn_global_load_lds(
        (const __attribute__((address_space(1))) unsigned int*)g,
        (__attribute__((address_space(3))) unsigned int*)l, 16, 0, 0);
}

// ---------------- conversions ----------------
__global__ __launch_bounds__(256) void conv_x4(const float* __restrict__ x,
                                               unsigned short* __restrict__ xb, int n4) {
    int i = blockIdx.x * blockDim.x + threadIdx.x;
    if (i >= n4) return;
    float4 v = *(const float4*)&x[(size_t)i * 4];
    unsigned short o[4] = {f2b(v.x), f2b(v.y), f2b(v.z), f2b(v.w)};
    *(ushort2*)&xb[(size_t)i * 4] = make_ushort2(o[0], o[1]);
    *(ushort2*)&xb[(size_t)i * 4 + 2] = make_ushort2(o[2], o[3]);
}

// all weights fp32 [K][N] -> bf16 [N][K], one dispatch
#define W1_SZ (512 * 256)
#define W2_SZ (512 * 512)
#define W3_SZ (64 * 512)
__global__ __launch_bounds__(256) void conv_wt_all(const float* __restrict__ W1,
                                                   const float* __restrict__ W2,
                                                   const float* __restrict__ W3,
                                                   const float* __restrict__ Wr3,
                                                   unsigned short* __restrict__ Wt1,
                                                   unsigned short* __restrict__ Wt2,
                                                   unsigned short* __restrict__ Wt3) {
    int o = blockIdx.x * blockDim.x + threadIdx.x;
    if (o < W1_SZ) {
        int n = o / 256, k = o % 256;
        Wt1[o] = f2b(W1[(size_t)k * 512 + n]);
    } else if (o < W1_SZ + W2_SZ) {
        int oo = o - W1_SZ;
        int n = oo / 512, k = oo % 512;
        Wt2[oo] = f2b(W2[(size_t)k * 512 + n]);
    } else if (o < W1_SZ + W2_SZ + W3_SZ) {
        int oo = o - W1_SZ - W2_SZ;
        int n = oo / 512, k = oo % 512;
        Wt3[oo] = f2b(W3[(size_t)k * 64 + n]);
    } else if (o < W1_SZ + W2_SZ + 2 * W3_SZ) {
        int oo = o - W1_SZ - W2_SZ - W3_SZ;
        int n = oo / 512, k = oo % 512;
        Wt3[W3_SZ + oo] = f2b(Wr3[(size_t)k * 64 + n]);
    }
}

// ---------------- bf16 MFMA GEMM with fused el/er epilogue ----------------
// C[M][NN] = A[M][K] @ Bt[NN][K]^T ; each 128-col block covers 2 heads (64 cols each).
template <int H, bool ELER>
__global__ __launch_bounds__(256, 2) void gemm_mfma(const unsigned short* __restrict__ A,
                                                    const unsigned short* __restrict__ Bt,
                                                    unsigned short* __restrict__ C,
                                                    const float* __restrict__ al,
                                                    const float* __restrict__ ar,
                                                    float* __restrict__ el,
                                                    float* __restrict__ er,
                                                    int M, int NN, int K) {
    __shared__ unsigned short As[128 * 32];
    __shared__ unsigned short Bs[128 * 32];
    const int tid = threadIdx.x;
    const int w = tid >> 6, l = tid & 63;
    const int bm = blockIdx.y * 128, bn = blockIdx.x * 128;
    const int wr = w >> 1, wc = w & 1;
    const int rA = l >> 2;
    const int kA = (l & 3) * 8;
    const int fr = l & 15, fq = l >> 4;
    f32x4 acc[4][4] = {};

    for (int k0 = 0; k0 < K; k0 += 32) {
#pragma unroll
        for (int j = 0; j < 2; ++j) {
            int row = w * 32 + j * 16 + rA;
            gload_lds16(&A[(size_t)(bm + row) * K + k0 + kA], &As[(w * 2 + j) * 512]);
            gload_lds16(&Bt[(size_t)(bn + row) * K + k0 + kA], &Bs[(w * 2 + j) * 512]);
        }
        __syncthreads();
        short8 a[4], b[4];
#pragma unroll
        for (int m = 0; m < 4; ++m)
            a[m] = *(const short8*)&As[(wr * 64 + m * 16 + fr) * 32 + fq * 8];
#pragma unroll
        for (int n = 0; n < 4; ++n)
            b[n] = *(const short8*)&Bs[(wc * 64 + n * 16 + fr) * 32 + fq * 8];
#pragma unroll
        for (int m = 0; m < 4; ++m)
#pragma unroll
            for (int n = 0; n < 4; ++n)
                acc[m][n] = __builtin_amdgcn_mfma_f32_16x16x32_bf16(a[m], b[n], acc[m][n], 0, 0, 0);
        __syncthreads();
    }

    // fused el/er: head = (bn>>6)+wc owns cols head*64..head*64+63 == this wave's wc half
    if (ELER) {
        const int head = (bn >> 6) + wc;
        if (head < H) {
            float alv[4], arv[4];
#pragma unroll
            for (int n = 0; n < 4; ++n) {
                alv[n] = al[head * 64 + n * 16 + fr];
                arv[n] = ar[head * 64 + n * 16 + fr];
            }
#pragma unroll
            for (int m = 0; m < 4; ++m) {
#pragma unroll
                for (int j = 0; j < 4; ++j) {
                    float pl = acc[m][0][j] * alv[0] + acc[m][1][j] * alv[1] +
                               acc[m][2][j] * alv[2] + acc[m][3][j] * alv[3];
                    float pr = acc[m][0][j] * arv[0] + acc[m][1][j] * arv[1] +
                               acc[m][2][j] * arv[2] + acc[m][3][j] * arv[3];
#pragma unroll
                    for (int off = 1; off < 16; off <<= 1) {
                        pl += __shfl_xor(pl, off);
                        pr += __shfl_xor(pr, off);
                    }
                    int r = bm + wr * 64 + m * 16 + fq * 4 + j;
                    if (fr == 0 && r < M) {
                        el[(size_t)r * H + head] = pl;
                        er[(size_t)r * H + head] = pr;
                    }
                }
            }
        }
    }

#pragma unroll
    for (int m = 0; m < 4; ++m) {
#pragma unroll
        for (int j = 0; j < 4; ++j) {
            int r = bm + wr * 64 + m * 16 + fq * 4 + j;
            if (r < M) {
#pragma unroll
                for (int n = 0; n < 4; ++n)
                    C[(size_t)r * NN + bn + wc * 64 + n * 16 + fr] = f2b(acc[m][n][j]);
            }
        }
    }
}

// ---------------- CSR build ----------------
__global__ __launch_bounds__(256) void hist_k(const int* __restrict__ dst,
                                              int* __restrict__ deg, int E) {
    int i = blockIdx.x * blockDim.x + threadIdx.x;
    if (i < E) atomicAdd(&deg[dst[i]], 1);
}

__global__ __launch_bounds__(SCAN_B) void scan_blocks(const int* __restrict__ in,
                                                      int* __restrict__ out,
                                                      int* __restrict__ part, int n) {
    __shared__ int tmp[SCAN_B];
    int t = threadIdx.x, g = blockIdx.x * SCAN_B + t;
    int v = (g < n) ? in[g] : 0;
    tmp[t] = v;
    __syncthreads();
    for (int off = 1; off < SCAN_B; off <<= 1) {
        int add = (t >= off) ? tmp[t - off] : 0;
        __syncthreads();
        tmp[t] += add;
        __syncthreads();
    }
    if (g < n) out[g] = tmp[t] - v;
    if (t == SCAN_B - 1) part[blockIdx.x] = tmp[t];
}

__global__ __launch_bounds__(SCAN_B) void scan_part(int* __restrict__ part, int n) {
    __shared__ int tmp[SCAN_B];
    int t = threadIdx.x;
    int v = (t < n) ? part[t] : 0;
    tmp[t] = v;
    __syncthreads();
    for (int off = 1; off < SCAN_B; off <<= 1) {
        int add = (t >= off) ? tmp[t - off] : 0;
        __syncthreads();
        tmp[t] += add;
        __syncthreads();
    }
    if (t < n) part[t] = tmp[t] - v;
}

__global__ __launch_bounds__(256) void add_off(int* __restrict__ rowptr,
                                               int* __restrict__ cursor,
                                               const int* __restrict__ part,
                                               int n, int E) {
    int g = blockIdx.x * blockDim.x + threadIdx.x;
    if (g < n) {
        int v = rowptr[g] + part[g / SCAN_B];
        rowptr[g] = v;
        cursor[g] = v;
    }
    if (g == 0) rowptr[n] = E;
}

__global__ __launch_bounds__(256) void scatter_k(const int* __restrict__ src,
                                                 const int* __restrict__ dst,
                                                 int* __restrict__ cursor,
                                                 int* __restrict__ csr_src, int E) {
    int e = blockIdx.x * blockDim.x + threadIdx.x;
    if (e < E) {
        int p = atomicAdd(&cursor[dst[e]], 1);
        csr_src[p] = src[e];
    }
}

// ---------------- fused GAT aggregation H=8, chunked phase 3 ----------------
template <bool HAS_INIT>
__global__ __launch_bounds__(256) void gat_agg8(const unsigned short* __restrict__ f,
                                                const float* __restrict__ el,
                                                const float* __restrict__ er,
                                                const int* __restrict__ rowptr,
                                                const int* __restrict__ csr_src,
                                                const unsigned short* __restrict__ init,
                                                const float* __restrict__ bias,
                                                unsigned short* __restrict__ outb, int N) {
    int w = (blockIdx.x * blockDim.x + threadIdx.x) >> 6;
    int lane = threadIdx.x & 63;
    if (w >= N) return;
    const int d = w;
    const int s0 = rowptr[d], s1 = rowptr[d + 1];
    const int hh = lane & 7;      // head for score phases
    const int esub = lane >> 3;   // edge sub-index for score phases
    const float erh = er[(size_t)d * 8 + hh];

    // phase 1: per-head max
    float mx = -1e30f;
    for (int i = s0 + esub; i < s1; i += 8) {
        float v = el[(size_t)csr_src[i] * 8 + hh] + erh;
        v = v > 0.f ? v : 0.2f * v;
        mx = fmaxf(mx, v);
    }
#pragma unroll
    for (int off = 8; off < 64; off <<= 1) mx = fmaxf(mx, __shfl_xor(mx, off));

    // phase 2: per-head sum of exp
    float sm = 0.f;
    for (int i = s0 + esub; i < s1; i += 8) {
        float v = el[(size_t)csr_src[i] * 8 + hh] + erh;
        v = v > 0.f ? v : 0.2f * v;
        sm += __expf(v - mx);
    }
#pragma unroll
    for (int off = 8; off < 64; off <<= 1) sm += __shfl_xor(sm, off);
    const float inv = sm > 0.f ? 1.0f / sm : 0.f;

    // phase 3: 8-edge chunks. Alpha batch: lane=(edge esub, head hh).
    // Gather: lane=(head lane>>3, slice lane&7) -> f offset = lane*8 (coalesced 1KB/edge).
    const int myhead = lane >> 3;
    const int sl8 = lane * 8;
    float acc[8] = {};
    for (int i0 = s0; i0 < s1; i0 += 8) {
        int i = i0 + esub;
        bool valid = i < s1;
        int sn_mine = csr_src[valid ? i : s0];
        float v = el[(size_t)sn_mine * 8 + hh] + erh;
        v = v > 0.f ? v : 0.2f * v;
        float am = valid ? __expf(v - mx) * inv : 0.f;
#pragma unroll
        for (int j = 0; j < 8; ++j) {
            if (i0 + j >= s1) break;                       // wave-uniform
            float alpha = __shfl(am, (j << 3) | myhead);   // alpha(edge j, my head)
            int sn = __shfl(sn_mine, j << 3);
            uint4 pk = *(const uint4*)&f[(size_t)sn * 512 + sl8];
            acc[0] += blo(pk.x) * alpha;
            acc[1] += bhi(pk.x) * alpha;
            acc[2] += blo(pk.y) * alpha;
            acc[3] += bhi(pk.y) * alpha;
            acc[4] += blo(pk.z) * alpha;
            acc[5] += bhi(pk.z) * alpha;
            acc[6] += blo(pk.w) * alpha;
            acc[7] += bhi(pk.w) * alpha;
        }
    }

    // epilogue
    const int sl = (lane & 7) * 8;
    float4 b0 = *(const float4*)&bias[myhead * 64 + sl];
    float4 b1 = *(const float4*)&bias[myhead * 64 + sl + 4];
    float bb[8] = {b0.x, b0.y, b0.z, b0.w, b1.x, b1.y, b1.z, b1.w};
    if (HAS_INIT) {
        uint4 iv = *(const uint4*)&init[(size_t)d * 512 + sl8];
        acc[0] += blo(iv.x); acc[1] += bhi(iv.x);
        acc[2] += blo(iv.y); acc[3] += bhi(iv.y);
        acc[4] += blo(iv.z); acc[5] += bhi(iv.z);
        acc[6] += blo(iv.w); acc[7] += bhi(iv.w);
    }
    unsigned short ob[8];
#pragma unroll
    for (int j = 0; j < 8; ++j) {
        float v = acc[j] + bb[j];
        v = v > 0.f ? v : __expf(v) - 1.f;
        ob[j] = f2b(v);
    }
    uint4 ov;
    ov.x = (unsigned)ob[0] | ((unsigned)ob[1] << 16);
    ov.y = (unsigned)ob[2] | ((unsigned)ob[3] << 16);
    ov.z = (unsigned)ob[4] | ((unsigned)ob[5] << 16);
    ov.w = (unsigned)ob[6] | ((unsigned)ob[7] << 16);
    *(uint4*)&outb[(size_t)d * 512 + sl8] = ov;
}

// ---------------- fused GAT aggregation H=1 (layer 3) ----------------
__global__ __launch_bounds__(256) void gat_agg1(const unsigned short* __restrict__ f, // [*,128]
                                                const float* __restrict__ el,
                                                const float* __restrict__ er,
                                                const int* __restrict__ rowptr,
                                                const int* __restrict__ csr_src,
                                                const float* __restrict__ bias,
                                                float* __restrict__ outf, int N) {
    int w = (blockIdx.x * blockDim.x + threadIdx.x) >> 6;
    int lane = threadIdx.x & 63;
    if (w >= N) return;
    const int d = w;
    const int s0 = rowptr[d], s1 = rowptr[d + 1];
    const float erh = er[d];

    float mx = -1e30f;
    for (int i = s0 + lane; i < s1; i += 64) {
        float v = el[csr_src[i]] + erh;
        v = v > 0.f ? v : 0.2f * v;
        mx = fmaxf(mx, v);
    }
#pragma unroll
    for (int off = 1; off < 64; off <<= 1) mx = fmaxf(mx, __shfl_xor(mx, off));

    float sm = 0.f;
    for (int i = s0 + lane; i < s1; i += 64) {
        float v = el[csr_src[i]] + erh;
        v = v > 0.f ? v : 0.2f * v;
        sm += __expf(v - mx);
    }
#pragma unroll
    for (int off = 1; off < 64; off <<= 1) sm += __shfl_xor(sm, off);
    const float inv = sm > 0.f ? 1.0f / sm : 0.f;

    const int esub = lane >> 3, sl = (lane & 7) * 8;
    float acc[8] = {};
    for (int i0 = s0; i0 < s1; i0 += 8) {
        int i = i0 + esub;
        bool valid = i < s1;
        int sn = csr_src[valid ? i : s0];
        float v = el[sn] + erh;
        v = v > 0.f ? v : 0.2f * v;
        float alpha = valid ? __expf(v - mx) * inv : 0.f;
        uint4 pk = *(const uint4*)&f[(size_t)sn * 128 + sl];
        acc[0] += blo(pk.x) * alpha;
        acc[1] += bhi(pk.x) * alpha;
        acc[2] += blo(pk.y) * alpha;
        acc[3] += bhi(pk.y) * alpha;
        acc[4] += blo(pk.z) * alpha;
        acc[5] += bhi(pk.z) * alpha;
        acc[6] += blo(pk.w) * alpha;
        acc[7] += bhi(pk.w) * alpha;
    }
#pragma unroll
    for (int off = 8; off < 64; off <<= 1)
#pragma unroll
        for (int j = 0; j < 8; ++j) acc[j] += __shfl_xor(acc[j], off);

    if (esub == 0) {
        uint4 rv = *(const uint4*)&f[(size_t)d * 128 + 64 + sl];
        float rr[8] = {blo(rv.x), bhi(rv.x), blo(rv.y), bhi(rv.y),
                       blo(rv.z), bhi(rv.z), blo(rv.w), bhi(rv.w)};
#pragma unroll
        for (int j = 0; j < 8; ++j)
            outf[(size_t)d * 64 + sl + j] = acc[j] + bias[sl + j] + rr[j];
    }
}

extern "C" void kernel_launch(void* const* d_in, const int* in_sizes, int n_in,
                              void* d_out, int out_size, void* d_ws, size_t ws_size,
                              hipStream_t stream) {
    const float* x   = (const float*)d_in[0];
    const int*   src = (const int*)d_in[1];
    const int*   dst = (const int*)d_in[2];
    const float* W1  = (const float*)d_in[3];
    const float* al1 = (const float*)d_in[4];
    const float* ar1 = (const float*)d_in[5];
    const float* b1  = (const float*)d_in[6];
    const float* W2  = (const float*)d_in[7];
    const float* al2 = (const float*)d_in[8];
    const float* ar2 = (const float*)d_in[9];
    const float* b2  = (const float*)d_in[10];
    const float* W3  = (const float*)d_in[11];
    const float* al3 = (const float*)d_in[12];
    const float* ar3 = (const float*)d_in[13];
    const float* b3  = (const float*)d_in[14];
    const float* Wr3 = (const float*)d_in[15];
    float* out = (float*)d_out;

    unsigned short* xb   = (unsigned short*)d_ws;               // [M_PAD][256]
    unsigned short* fb   = xb + (size_t)M_PAD * 256;            // [M_PAD][512]
    unsigned short* h1b  = fb + (size_t)M_PAD * 512;            // [M_PAD][512]
    unsigned short* h2b  = h1b + (size_t)M_PAD * 512;           // [M_PAD][512]
    unsigned short* f3r  = h2b + (size_t)M_PAD * 512;           // [M_PAD][128]
    unsigned short* Wt1  = f3r + (size_t)M_PAD * 128;           // [512][256]
    unsigned short* Wt2  = Wt1 + 512 * 256;                     // [512][512]
    unsigned short* Wt3  = Wt2 + 512 * 512;                     // [128][512]
    float* el = (float*)(Wt3 + 128 * 512);                      // N*8
    float* er = el + (size_t)N_NODES * 8;                       // N*8
    int* rowptr  = (int*)(er + (size_t)N_NODES * 8);            // N+1
    int* cursor  = rowptr + (N_NODES + 1);
    int* part    = cursor + N_NODES;
    int* csr_src = part + 256;                                  // E

    const dim3 blk(256);
    const int E = N_EDGES, N = N_NODES;
    const int nb = (N + SCAN_B - 1) / SCAN_B;
    const int gy = (N + 127) / 128;

    conv_x4<<<(N * 64 + 255) / 256, blk, 0, stream>>>(x, xb, N * 64);
    conv_wt_all<<<(W1_SZ + W2_SZ + 2 * W3_SZ + 255) / 256, blk, 0, stream>>>(
        W1, W2, W3, Wr3, Wt1, Wt2, Wt3);

    hipMemsetAsync(cursor, 0, (size_t)N * 4, stream);
    hist_k<<<(E + 255) / 256, blk, 0, stream>>>(dst, cursor, E);
    scan_blocks<<<nb, SCAN_B, 0, stream>>>(cursor, rowptr, part, N);
    scan_part<<<1, SCAN_B, 0, stream>>>(part, nb);
    add_off<<<nb, blk, 0, stream>>>(rowptr, cursor, part, N, E);
    scatter_k<<<(E + 255) / 256, blk, 0, stream>>>(src, dst, cursor, csr_src, E);

    // ================= layer 1 =================
    gemm_mfma<8, true><<<dim3(4, gy), blk, 0, stream>>>(
        xb, Wt1, fb, al1, ar1, el, er, N, 512, 256);
    gat_agg8<false><<<(N + 3) / 4, blk, 0, stream>>>(
        fb, el, er, rowptr, csr_src, nullptr, b1, h1b, N);

    // ================= layer 2 (identity residual = h1) =================
    gemm_mfma<8, true><<<dim3(4, gy), blk, 0, stream>>>(
        h1b, Wt2, fb, al2, ar2, el, er, N, 512, 512);
    gat_agg8<true><<<(N + 3) / 4, blk, 0, stream>>>(
        fb, el, er, rowptr, csr_src, h1b, b2, h2b, N);

    // ================= layer 3 (1 head, projected residual) =================
    gemm_mfma<1, true><<<dim3(1, gy), blk, 0, stream>>>(
        h2b, Wt3, f3r, al3, ar3, el, er, N, 128, 512);
    gat_agg1<<<(N + 3) / 4, blk, 0, stream>>>(
        f3r, el, er, rowptr, csr_src, b3, out, N);
}

// Round 6
// 357.048 us; speedup vs baseline: 6.7448x; 1.0352x over previous
//
#include <hip/hip_runtime.h>
#include <hip/hip_bf16.h>

#define N_NODES 50000
#define M_PAD 50048
#define N_EDGES 400000
#define SCAN_B 256

typedef __attribute__((ext_vector_type(8))) short short8;
typedef __attribute__((ext_vector_type(4))) float f32x4;

__device__ __forceinline__ float b2f(unsigned short u) {
    return __uint_as_float(((unsigned)u) << 16);
}
__device__ __forceinline__ unsigned short f2b(float f) {
    unsigned u = __float_as_uint(f);
    return (unsigned short)((u + 0x7fffu + ((u >> 16) & 1u)) >> 16);
}
__device__ __forceinline__ float blo(unsigned u) { return __uint_as_float(u << 16); }
__device__ __forceinline__ float bhi(unsigned u) { return __uint_as_float(u & 0xffff0000u); }

__device__ __forceinline__ void gload_lds16(const void* g, void* l) {
    __builtin_amdgcn_global_load_lds(
        (const __attribute__((address_space(1))) unsigned int*)g,
        (__attribute__((address_space(3))) unsigned int*)l, 16, 0, 0);
}

// ---------------- fused prep: x->bf16 + all weights fp32[K][N]->bf16[N][K] ----------------
#define X4_N (N_NODES * 64)
#define W1_SZ (512 * 256)
#define W2_SZ (512 * 512)
#define W3_SZ (64 * 512)
__global__ __launch_bounds__(256) void prep_k(const float* __restrict__ x,
                                              const float* __restrict__ W1,
                                              const float* __restrict__ W2,
                                              const float* __restrict__ W3,
                                              const float* __restrict__ Wr3,
                                              unsigned short* __restrict__ xb,
                                              unsigned short* __restrict__ Wt1,
                                              unsigned short* __restrict__ Wt2,
                                              unsigned short* __restrict__ Wt3) {
    int i = blockIdx.x * blockDim.x + threadIdx.x;
    if (i < X4_N) {
        float4 v = *(const float4*)&x[(size_t)i * 4];
        unsigned short o[4] = {f2b(v.x), f2b(v.y), f2b(v.z), f2b(v.w)};
        *(ushort2*)&xb[(size_t)i * 4] = make_ushort2(o[0], o[1]);
        *(ushort2*)&xb[(size_t)i * 4 + 2] = make_ushort2(o[2], o[3]);
        return;
    }
    int o = i - X4_N;
    if (o < W1_SZ) {
        int n = o / 256, k = o % 256;
        Wt1[o] = f2b(W1[(size_t)k * 512 + n]);
    } else if (o < W1_SZ + W2_SZ) {
        int oo = o - W1_SZ;
        int n = oo / 512, k = oo % 512;
        Wt2[oo] = f2b(W2[(size_t)k * 512 + n]);
    } else if (o < W1_SZ + W2_SZ + W3_SZ) {
        int oo = o - W1_SZ - W2_SZ;
        int n = oo / 512, k = oo % 512;
        Wt3[oo] = f2b(W3[(size_t)k * 64 + n]);
    } else if (o < W1_SZ + W2_SZ + 2 * W3_SZ) {
        int oo = o - W1_SZ - W2_SZ - W3_SZ;
        int n = oo / 512, k = oo % 512;
        Wt3[W3_SZ + oo] = f2b(Wr3[(size_t)k * 64 + n]);
    }
}

// ---------------- bf16 MFMA GEMM with fused el/er epilogue ----------------
template <int H, bool ELER>
__global__ __launch_bounds__(256, 2) void gemm_mfma(const unsigned short* __restrict__ A,
                                                    const unsigned short* __restrict__ Bt,
                                                    unsigned short* __restrict__ C,
                                                    const float* __restrict__ al,
                                                    const float* __restrict__ ar,
                                                    float* __restrict__ el,
                                                    float* __restrict__ er,
                                                    int M, int NN, int K) {
    __shared__ unsigned short As[128 * 32];
    __shared__ unsigned short Bs[128 * 32];
    const int tid = threadIdx.x;
    const int w = tid >> 6, l = tid & 63;
    const int bm = blockIdx.y * 128, bn = blockIdx.x * 128;
    const int wr = w >> 1, wc = w & 1;
    const int rA = l >> 2;
    const int kA = (l & 3) * 8;
    const int fr = l & 15, fq = l >> 4;
    f32x4 acc[4][4] = {};

    for (int k0 = 0; k0 < K; k0 += 32) {
#pragma unroll
        for (int j = 0; j < 2; ++j) {
            int row = w * 32 + j * 16 + rA;
            gload_lds16(&A[(size_t)(bm + row) * K + k0 + kA], &As[(w * 2 + j) * 512]);
            gload_lds16(&Bt[(size_t)(bn + row) * K + k0 + kA], &Bs[(w * 2 + j) * 512]);
        }
        __syncthreads();
        short8 a[4], b[4];
#pragma unroll
        for (int m = 0; m < 4; ++m)
            a[m] = *(const short8*)&As[(wr * 64 + m * 16 + fr) * 32 + fq * 8];
#pragma unroll
        for (int n = 0; n < 4; ++n)
            b[n] = *(const short8*)&Bs[(wc * 64 + n * 16 + fr) * 32 + fq * 8];
#pragma unroll
        for (int m = 0; m < 4; ++m)
#pragma unroll
            for (int n = 0; n < 4; ++n)
                acc[m][n] = __builtin_amdgcn_mfma_f32_16x16x32_bf16(a[m], b[n], acc[m][n], 0, 0, 0);
        __syncthreads();
    }

    if (ELER) {
        const int head = (bn >> 6) + wc;
        if (head < H) {
            float alv[4], arv[4];
#pragma unroll
            for (int n = 0; n < 4; ++n) {
                alv[n] = al[head * 64 + n * 16 + fr];
                arv[n] = ar[head * 64 + n * 16 + fr];
            }
#pragma unroll
            for (int m = 0; m < 4; ++m) {
#pragma unroll
                for (int j = 0; j < 4; ++j) {
                    float pl = acc[m][0][j] * alv[0] + acc[m][1][j] * alv[1] +
                               acc[m][2][j] * alv[2] + acc[m][3][j] * alv[3];
                    float pr = acc[m][0][j] * arv[0] + acc[m][1][j] * arv[1] +
                               acc[m][2][j] * arv[2] + acc[m][3][j] * arv[3];
#pragma unroll
                    for (int off = 1; off < 16; off <<= 1) {
                        pl += __shfl_xor(pl, off);
                        pr += __shfl_xor(pr, off);
                    }
                    int r = bm + wr * 64 + m * 16 + fq * 4 + j;
                    if (fr == 0 && r < M) {
                        el[(size_t)r * H + head] = pl;
                        er[(size_t)r * H + head] = pr;
                    }
                }
            }
        }
    }

#pragma unroll
    for (int m = 0; m < 4; ++m) {
#pragma unroll
        for (int j = 0; j < 4; ++j) {
            int r = bm + wr * 64 + m * 16 + fq * 4 + j;
            if (r < M) {
#pragma unroll
                for (int n = 0; n < 4; ++n)
                    C[(size_t)r * NN + bn + wc * 64 + n * 16 + fr] = f2b(acc[m][n][j]);
            }
        }
    }
}

// ---------------- CSR build ----------------
__global__ __launch_bounds__(256) void hist_k(const int* __restrict__ dst,
                                              int* __restrict__ deg, int E) {
    int i = blockIdx.x * blockDim.x + threadIdx.x;
    if (i < E) atomicAdd(&deg[dst[i]], 1);
}

__global__ __launch_bounds__(SCAN_B) void scan_blocks(const int* __restrict__ in,
                                                      int* __restrict__ out,
                                                      int* __restrict__ part, int n) {
    __shared__ int tmp[SCAN_B];
    int t = threadIdx.x, g = blockIdx.x * SCAN_B + t;
    int v = (g < n) ? in[g] : 0;
    tmp[t] = v;
    __syncthreads();
    for (int off = 1; off < SCAN_B; off <<= 1) {
        int add = (t >= off) ? tmp[t - off] : 0;
        __syncthreads();
        tmp[t] += add;
        __syncthreads();
    }
    if (g < n) out[g] = tmp[t] - v;
    if (t == SCAN_B - 1) part[blockIdx.x] = tmp[t];
}

__global__ __launch_bounds__(SCAN_B) void scan_part(int* __restrict__ part, int n) {
    __shared__ int tmp[SCAN_B];
    int t = threadIdx.x;
    int v = (t < n) ? part[t] : 0;
    tmp[t] = v;
    __syncthreads();
    for (int off = 1; off < SCAN_B; off <<= 1) {
        int add = (t >= off) ? tmp[t - off] : 0;
        __syncthreads();
        tmp[t] += add;
        __syncthreads();
    }
    if (t < n) part[t] = tmp[t] - v;
}

__global__ __launch_bounds__(256) void add_off(int* __restrict__ rowptr,
                                               int* __restrict__ cursor,
                                               const int* __restrict__ part,
                                               int n, int E) {
    int g = blockIdx.x * blockDim.x + threadIdx.x;
    if (g < n) {
        int v = rowptr[g] + part[g / SCAN_B];
        rowptr[g] = v;
        cursor[g] = v;
    }
    if (g == 0) rowptr[n] = E;
}

__global__ __launch_bounds__(256) void scatter_k(const int* __restrict__ src,
                                                 const int* __restrict__ dst,
                                                 int* __restrict__ cursor,
                                                 int* __restrict__ csr_src, int E) {
    int e = blockIdx.x * blockDim.x + threadIdx.x;
    if (e < E) {
        int p = atomicAdd(&cursor[dst[e]], 1);
        csr_src[p] = src[e];
    }
}

// ---------------- fused GAT aggregation H=8: gathers issued before softmax ----------------
template <bool HAS_INIT>
__global__ __launch_bounds__(256) void gat_agg8(const unsigned short* __restrict__ f,
                                                const float* __restrict__ el,
                                                const float* __restrict__ er,
                                                const int* __restrict__ rowptr,
                                                const int* __restrict__ csr_src,
                                                const unsigned short* __restrict__ init,
                                                const float* __restrict__ bias,
                                                unsigned short* __restrict__ outb, int N) {
    int w = (blockIdx.x * blockDim.x + threadIdx.x) >> 6;
    int lane = threadIdx.x & 63;
    if (w >= N) return;
    const int d = w;
    const int s0 = rowptr[d], s1 = rowptr[d + 1];
    const int hh = lane & 7;      // head for score lanes
    const int esub = lane >> 3;   // edge sub-index for score lanes
    const int myhead = lane >> 3; // head for gather lanes
    const int sl8 = lane * 8;     // = myhead*64 + (lane&7)*8
    const float erh = er[(size_t)d * 8 + hh];

    // ---- chunk 0: load sn, issue all 8 row-gathers immediately (alpha applied later) ----
    int i0 = s0 + esub;
    bool valid0 = i0 < s1;
    int sn0 = csr_src[valid0 ? i0 : s0];  // csr_src padded: index E is valid (0)
    uint4 pk[8];
#pragma unroll
    for (int j = 0; j < 8; ++j) {
        int snj = __shfl(sn0, j << 3);
        pk[j] = *(const uint4*)&f[(size_t)snj * 512 + sl8];
    }

    // ---- softmax (concurrent with in-flight gathers) ----
    float v0 = el[(size_t)sn0 * 8 + hh] + erh;
    v0 = v0 > 0.f ? v0 : 0.2f * v0;
    float mx = valid0 ? v0 : -1e30f;
    for (int i = s0 + 8 + esub; i < s1; i += 8) {
        float v = el[(size_t)csr_src[i] * 8 + hh] + erh;
        v = v > 0.f ? v : 0.2f * v;
        mx = fmaxf(mx, v);
    }
    mx = fmaxf(mx, __shfl_xor(mx, 8));
    mx = fmaxf(mx, __shfl_xor(mx, 16));
    mx = fmaxf(mx, __shfl_xor(mx, 32));

    float am0 = valid0 ? __expf(v0 - mx) : 0.f;  // unnormalized
    float sm = am0;
    float acc[8] = {};
#pragma unroll
    for (int j = 0; j < 8; ++j) {
        float alpha = __shfl(am0, (j << 3) | myhead);
        acc[0] += blo(pk[j].x) * alpha;
        acc[1] += bhi(pk[j].x) * alpha;
        acc[2] += blo(pk[j].y) * alpha;
        acc[3] += bhi(pk[j].y) * alpha;
        acc[4] += blo(pk[j].z) * alpha;
        acc[5] += bhi(pk[j].z) * alpha;
        acc[6] += blo(pk[j].w) * alpha;
        acc[7] += bhi(pk[j].w) * alpha;
    }

    // ---- remaining chunks (degree > 8) ----
    for (int ii = s0 + 8; ii < s1; ii += 8) {
        int i = ii + esub;
        bool valid = i < s1;
        int sn_mine = csr_src[valid ? i : s0];
        uint4 qk[8];
#pragma unroll
        for (int j = 0; j < 8; ++j) {
            int snj = __shfl(sn_mine, j << 3);
            qk[j] = *(const uint4*)&f[(size_t)snj * 512 + sl8];
        }
        float v = el[(size_t)sn_mine * 8 + hh] + erh;
        v = v > 0.f ? v : 0.2f * v;
        float am = valid ? __expf(v - mx) : 0.f;
        sm += am;
#pragma unroll
        for (int j = 0; j < 8; ++j) {
            float alpha = __shfl(am, (j << 3) | myhead);
            acc[0] += blo(qk[j].x) * alpha;
            acc[1] += bhi(qk[j].x) * alpha;
            acc[2] += blo(qk[j].y) * alpha;
            acc[3] += bhi(qk[j].y) * alpha;
            acc[4] += blo(qk[j].z) * alpha;
            acc[5] += bhi(qk[j].z) * alpha;
            acc[6] += blo(qk[j].w) * alpha;
            acc[7] += bhi(qk[j].w) * alpha;
        }
    }

    // ---- normalize ----
    sm += __shfl_xor(sm, 8);
    sm += __shfl_xor(sm, 16);
    sm += __shfl_xor(sm, 32);
    float smh = __shfl(sm, myhead);   // lane 'myhead' has hh == myhead
    float inv = smh > 0.f ? 1.0f / smh : 0.f;
#pragma unroll
    for (int j = 0; j < 8; ++j) acc[j] *= inv;

    // ---- epilogue ----
    const int sl = (lane & 7) * 8;
    float4 b0 = *(const float4*)&bias[myhead * 64 + sl];
    float4 b1 = *(const float4*)&bias[myhead * 64 + sl + 4];
    float bb[8] = {b0.x, b0.y, b0.z, b0.w, b1.x, b1.y, b1.z, b1.w};
    if (HAS_INIT) {
        uint4 iv = *(const uint4*)&init[(size_t)d * 512 + sl8];
        acc[0] += blo(iv.x); acc[1] += bhi(iv.x);
        acc[2] += blo(iv.y); acc[3] += bhi(iv.y);
        acc[4] += blo(iv.z); acc[5] += bhi(iv.z);
        acc[6] += blo(iv.w); acc[7] += bhi(iv.w);
    }
    unsigned short ob[8];
#pragma unroll
    for (int j = 0; j < 8; ++j) {
        float v = acc[j] + bb[j];
        v = v > 0.f ? v : __expf(v) - 1.f;
        ob[j] = f2b(v);
    }
    uint4 ov;
    ov.x = (unsigned)ob[0] | ((unsigned)ob[1] << 16);
    ov.y = (unsigned)ob[2] | ((unsigned)ob[3] << 16);
    ov.z = (unsigned)ob[4] | ((unsigned)ob[5] << 16);
    ov.w = (unsigned)ob[6] | ((unsigned)ob[7] << 16);
    *(uint4*)&outb[(size_t)d * 512 + sl8] = ov;
}

// ---------------- fused GAT aggregation H=1 (layer 3) ----------------
__global__ __launch_bounds__(256) void gat_agg1(const unsigned short* __restrict__ f, // [*,128]
                                                const float* __restrict__ el,
                                                const float* __restrict__ er,
                                                const int* __restrict__ rowptr,
                                                const int* __restrict__ csr_src,
                                                const float* __restrict__ bias,
                                                float* __restrict__ outf, int N) {
    int w = (blockIdx.x * blockDim.x + threadIdx.x) >> 6;
    int lane = threadIdx.x & 63;
    if (w >= N) return;
    const int d = w;
    const int s0 = rowptr[d], s1 = rowptr[d + 1];
    const int esub = lane >> 3, sl = (lane & 7) * 8;
    const float erh = er[d];

    // chunk 0: own-edge gather issued before softmax
    int i0 = s0 + esub;
    bool valid0 = i0 < s1;
    int sn0 = csr_src[valid0 ? i0 : s0];
    uint4 pk0 = *(const uint4*)&f[(size_t)sn0 * 128 + sl];

    float v0 = el[sn0] + erh;
    v0 = v0 > 0.f ? v0 : 0.2f * v0;
    float mx = valid0 ? v0 : -1e30f;
    for (int i = s0 + 8 + esub; i < s1; i += 8) {
        float v = el[csr_src[i]] + erh;
        v = v > 0.f ? v : 0.2f * v;
        mx = fmaxf(mx, v);
    }
    mx = fmaxf(mx, __shfl_xor(mx, 8));
    mx = fmaxf(mx, __shfl_xor(mx, 16));
    mx = fmaxf(mx, __shfl_xor(mx, 32));

    float am0 = valid0 ? __expf(v0 - mx) : 0.f;
    float sm = am0;
    float acc[8];
    acc[0] = blo(pk0.x) * am0; acc[1] = bhi(pk0.x) * am0;
    acc[2] = blo(pk0.y) * am0; acc[3] = bhi(pk0.y) * am0;
    acc[4] = blo(pk0.z) * am0; acc[5] = bhi(pk0.z) * am0;
    acc[6] = blo(pk0.w) * am0; acc[7] = bhi(pk0.w) * am0;

    for (int ii = s0 + 8; ii < s1; ii += 8) {
        int i = ii + esub;
        bool valid = i < s1;
        int sn = csr_src[valid ? i : s0];
        uint4 pk = *(const uint4*)&f[(size_t)sn * 128 + sl];
        float v = el[sn] + erh;
        v = v > 0.f ? v : 0.2f * v;
        float am = valid ? __expf(v - mx) : 0.f;
        sm += am;
        acc[0] += blo(pk.x) * am; acc[1] += bhi(pk.x) * am;
        acc[2] += blo(pk.y) * am; acc[3] += bhi(pk.y) * am;
        acc[4] += blo(pk.z) * am; acc[5] += bhi(pk.z) * am;
        acc[6] += blo(pk.w) * am; acc[7] += bhi(pk.w) * am;
    }

    sm += __shfl_xor(sm, 8);
    sm += __shfl_xor(sm, 16);
    sm += __shfl_xor(sm, 32);
#pragma unroll
    for (int off = 8; off < 64; off <<= 1)
#pragma unroll
        for (int j = 0; j < 8; ++j) acc[j] += __shfl_xor(acc[j], off);
    float inv = sm > 0.f ? 1.0f / sm : 0.f;

    if (esub == 0) {
        uint4 rv = *(const uint4*)&f[(size_t)d * 128 + 64 + sl];
        float rr[8] = {blo(rv.x), bhi(rv.x), blo(rv.y), bhi(rv.y),
                       blo(rv.z), bhi(rv.z), blo(rv.w), bhi(rv.w)};
#pragma unroll
        for (int j = 0; j < 8; ++j)
            outf[(size_t)d * 64 + sl + j] = acc[j] * inv + bias[sl + j] + rr[j];
    }
}

extern "C" void kernel_launch(void* const* d_in, const int* in_sizes, int n_in,
                              void* d_out, int out_size, void* d_ws, size_t ws_size,
                              hipStream_t stream) {
    const float* x   = (const float*)d_in[0];
    const int*   src = (const int*)d_in[1];
    const int*   dst = (const int*)d_in[2];
    const float* W1  = (const float*)d_in[3];
    const float* al1 = (const float*)d_in[4];
    const float* ar1 = (const float*)d_in[5];
    const float* b1  = (const float*)d_in[6];
    const float* W2  = (const float*)d_in[7];
    const float* al2 = (const float*)d_in[8];
    const float* ar2 = (const float*)d_in[9];
    const float* b2  = (const float*)d_in[10];
    const float* W3  = (const float*)d_in[11];
    const float* al3 = (const float*)d_in[12];
    const float* ar3 = (const float*)d_in[13];
    const float* b3  = (const float*)d_in[14];
    const float* Wr3 = (const float*)d_in[15];
    float* out = (float*)d_out;

    unsigned short* xb   = (unsigned short*)d_ws;               // [M_PAD][256]
    unsigned short* fb   = xb + (size_t)M_PAD * 256;            // [M_PAD][512]
    unsigned short* h1b  = fb + (size_t)M_PAD * 512;            // [M_PAD][512]
    unsigned short* h2b  = h1b + (size_t)M_PAD * 512;           // [M_PAD][512]
    unsigned short* f3r  = h2b + (size_t)M_PAD * 512;           // [M_PAD][128]
    unsigned short* Wt1  = f3r + (size_t)M_PAD * 128;           // [512][256]
    unsigned short* Wt2  = Wt1 + 512 * 256;                     // [512][512]
    unsigned short* Wt3  = Wt2 + 512 * 512;                     // [128][512]
    float* el = (float*)(Wt3 + 128 * 512);                      // N*8
    float* er = el + (size_t)N_NODES * 8;                       // N*8
    int* rowptr  = (int*)(er + (size_t)N_NODES * 8);            // N+1
    int* cursor  = rowptr + (N_NODES + 1);
    int* part    = cursor + N_NODES;
    int* csr_src = part + 256;                                  // E + 8 pad

    const dim3 blk(256);
    const int E = N_EDGES, N = N_NODES;
    const int nb = (N + SCAN_B - 1) / SCAN_B;
    const int gy = (N + 127) / 128;

    prep_k<<<(X4_N + W1_SZ + W2_SZ + 2 * W3_SZ + 255) / 256, blk, 0, stream>>>(
        x, W1, W2, W3, Wr3, xb, Wt1, Wt2, Wt3);

    hipMemsetAsync(cursor, 0, (size_t)N * 4, stream);
    hipMemsetAsync(csr_src + E, 0, 8 * 4, stream);   // pad: valid node id 0
    hist_k<<<(E + 255) / 256, blk, 0, stream>>>(dst, cursor, E);
    scan_blocks<<<nb, SCAN_B, 0, stream>>>(cursor, rowptr, part, N);
    scan_part<<<1, SCAN_B, 0, stream>>>(part, nb);
    add_off<<<nb, blk, 0, stream>>>(rowptr, cursor, part, N, E);
    scatter_k<<<(E + 255) / 256, blk, 0, stream>>>(src, dst, cursor, csr_src, E);

    // ================= layer 1 =================
    gemm_mfma<8, true><<<dim3(4, gy), blk, 0, stream>>>(
        xb, Wt1, fb, al1, ar1, el, er, N, 512, 256);
    gat_agg8<false><<<(N + 3) / 4, blk, 0, stream>>>(
        fb, el, er, rowptr, csr_src, nullptr, b1, h1b, N);

    // ================= layer 2 (identity residual = h1) =================
    gemm_mfma<8, true><<<dim3(4, gy), blk, 0, stream>>>(
        h1b, Wt2, fb, al2, ar2, el, er, N, 512, 512);
    gat_agg8<true><<<(N + 3) / 4, blk, 0, stream>>>(
        fb, el, er, rowptr, csr_src, h1b, b2, h2b, N);

    // ================= layer 3 (1 head, projected residual) =================
    gemm_mfma<1, true><<<dim3(1, gy), blk, 0, stream>>>(
        h2b, Wt3, f3r, al3, ar3, el, er, N, 128, 512);
    gat_agg1<<<(N + 3) / 4, blk, 0, stream>>>(
        f3r, el, er, rowptr, csr_src, b3, out, N);
}

// Round 7
// 343.738 us; speedup vs baseline: 7.0060x; 1.0387x over previous
//
#include <hip/hip_runtime.h>
#include <hip/hip_bf16.h>

#define N_NODES 50000
#define M_PAD 50048
#define N_EDGES 400000
#define SCAN_B 256

typedef __attribute__((ext_vector_type(8))) short short8;
typedef __attribute__((ext_vector_type(4))) float f32x4;

__device__ __forceinline__ unsigned short f2b(float f) {
    unsigned u = __float_as_uint(f);
    return (unsigned short)((u + 0x7fffu + ((u >> 16) & 1u)) >> 16);
}
__device__ __forceinline__ float blo(unsigned u) { return __uint_as_float(u << 16); }
__device__ __forceinline__ float bhi(unsigned u) { return __uint_as_float(u & 0xffff0000u); }

__device__ __forceinline__ void gload_lds16(const void* g, void* l) {
    __builtin_amdgcn_global_load_lds(
        (const __attribute__((address_space(1))) unsigned int*)g,
        (__attribute__((address_space(3))) unsigned int*)l, 16, 0, 0);
}

// ---------------- fused prep: x->bf16, weights->bf16 transposed, degree histogram ----------------
#define X4_N (N_NODES * 64)
#define W1_SZ (512 * 256)
#define W2_SZ (512 * 512)
#define W3_SZ (64 * 512)
#define WTOT (W1_SZ + W2_SZ + 2 * W3_SZ)
__global__ __launch_bounds__(256) void prep_k(const float* __restrict__ x,
                                              const float* __restrict__ W1,
                                              const float* __restrict__ W2,
                                              const float* __restrict__ W3,
                                              const float* __restrict__ Wr3,
                                              const int* __restrict__ dst,
                                              unsigned short* __restrict__ xb,
                                              unsigned short* __restrict__ Wt1,
                                              unsigned short* __restrict__ Wt2,
                                              unsigned short* __restrict__ Wt3,
                                              int* __restrict__ deg) {
    int i = blockIdx.x * blockDim.x + threadIdx.x;
    if (i < X4_N) {
        float4 v = *(const float4*)&x[(size_t)i * 4];
        unsigned short o[4] = {f2b(v.x), f2b(v.y), f2b(v.z), f2b(v.w)};
        *(ushort2*)&xb[(size_t)i * 4] = make_ushort2(o[0], o[1]);
        *(ushort2*)&xb[(size_t)i * 4 + 2] = make_ushort2(o[2], o[3]);
        return;
    }
    int o = i - X4_N;
    if (o < W1_SZ) {
        int n = o / 256, k = o % 256;
        Wt1[o] = f2b(W1[(size_t)k * 512 + n]);
    } else if (o < W1_SZ + W2_SZ) {
        int oo = o - W1_SZ;
        int n = oo / 512, k = oo % 512;
        Wt2[oo] = f2b(W2[(size_t)k * 512 + n]);
    } else if (o < W1_SZ + W2_SZ + W3_SZ) {
        int oo = o - W1_SZ - W2_SZ;
        int n = oo / 512, k = oo % 512;
        Wt3[oo] = f2b(W3[(size_t)k * 64 + n]);
    } else if (o < WTOT) {
        int oo = o - W1_SZ - W2_SZ - W3_SZ;
        int n = oo / 512, k = oo % 512;
        Wt3[W3_SZ + oo] = f2b(Wr3[(size_t)k * 64 + n]);
    } else {
        int e = o - WTOT;
        if (e < N_EDGES) atomicAdd(&deg[dst[e]], 1);
    }
}

// ---------------- bf16 MFMA GEMM, XCD-co-located row panels, fused el/er ----------------
// 1-D grid of NBX*nby blocks. Same-row col-blocks share bid%8 -> same XCD L2 -> A fetched once.
template <int H, int NBX, bool ELER>
__global__ __launch_bounds__(256, 2) void gemm_mfma(const unsigned short* __restrict__ A,
                                                    const unsigned short* __restrict__ Bt,
                                                    unsigned short* __restrict__ C,
                                                    const float* __restrict__ al,
                                                    const float* __restrict__ ar,
                                                    float* __restrict__ el,
                                                    float* __restrict__ er,
                                                    int M, int NN, int K) {
    const int nby = (M + 127) >> 7;
    int bid = blockIdx.x;
    int r, c;
    if (NBX == 4) {
        int full = nby & ~7;          // rows in complete 8-row groups
        int nfull = full * 4;
        if (bid < nfull) {
            r = (bid >> 5) * 8 + (bid & 7);
            c = (bid >> 3) & 3;
        } else {
            int t = bid - nfull, rem = nby - full;
            r = full + t % rem;
            c = t / rem;
        }
    } else {
        r = bid;
        c = 0;
    }
    __shared__ unsigned short As[128 * 32];
    __shared__ unsigned short Bs[128 * 32];
    const int tid = threadIdx.x;
    const int w = tid >> 6, l = tid & 63;
    const int bm = r * 128, bn = c * 128;
    const int wr = w >> 1, wc = w & 1;
    const int rA = l >> 2;
    const int kA = (l & 3) * 8;
    const int fr = l & 15, fq = l >> 4;
    f32x4 acc[4][4] = {};

    for (int k0 = 0; k0 < K; k0 += 32) {
#pragma unroll
        for (int j = 0; j < 2; ++j) {
            int row = w * 32 + j * 16 + rA;
            gload_lds16(&A[(size_t)(bm + row) * K + k0 + kA], &As[(w * 2 + j) * 512]);
            gload_lds16(&Bt[(size_t)(bn + row) * K + k0 + kA], &Bs[(w * 2 + j) * 512]);
        }
        __syncthreads();
        short8 a[4], b[4];
#pragma unroll
        for (int m = 0; m < 4; ++m)
            a[m] = *(const short8*)&As[(wr * 64 + m * 16 + fr) * 32 + fq * 8];
#pragma unroll
        for (int n = 0; n < 4; ++n)
            b[n] = *(const short8*)&Bs[(wc * 64 + n * 16 + fr) * 32 + fq * 8];
#pragma unroll
        for (int m = 0; m < 4; ++m)
#pragma unroll
            for (int n = 0; n < 4; ++n)
                acc[m][n] = __builtin_amdgcn_mfma_f32_16x16x32_bf16(a[m], b[n], acc[m][n], 0, 0, 0);
        __syncthreads();
    }

    if (ELER) {
        const int head = (bn >> 6) + wc;
        if (head < H) {
            float alv[4], arv[4];
#pragma unroll
            for (int n = 0; n < 4; ++n) {
                alv[n] = al[head * 64 + n * 16 + fr];
                arv[n] = ar[head * 64 + n * 16 + fr];
            }
#pragma unroll
            for (int m = 0; m < 4; ++m) {
#pragma unroll
                for (int j = 0; j < 4; ++j) {
                    float pl = acc[m][0][j] * alv[0] + acc[m][1][j] * alv[1] +
                               acc[m][2][j] * alv[2] + acc[m][3][j] * alv[3];
                    float pr = acc[m][0][j] * arv[0] + acc[m][1][j] * arv[1] +
                               acc[m][2][j] * arv[2] + acc[m][3][j] * arv[3];
#pragma unroll
                    for (int off = 1; off < 16; off <<= 1) {
                        pl += __shfl_xor(pl, off);
                        pr += __shfl_xor(pr, off);
                    }
                    int rr = bm + wr * 64 + m * 16 + fq * 4 + j;
                    if (fr == 0 && rr < M) {
                        el[(size_t)rr * H + head] = pl;
                        er[(size_t)rr * H + head] = pr;
                    }
                }
            }
        }
    }

#pragma unroll
    for (int m = 0; m < 4; ++m) {
#pragma unroll
        for (int j = 0; j < 4; ++j) {
            int rr = bm + wr * 64 + m * 16 + fq * 4 + j;
            if (rr < M) {
#pragma unroll
                for (int n = 0; n < 4; ++n)
                    C[(size_t)rr * NN + bn + wc * 64 + n * 16 + fr] = f2b(acc[m][n][j]);
            }
        }
    }
}

// ---------------- CSR build ----------------
__global__ __launch_bounds__(SCAN_B) void scan_blocks(const int* __restrict__ in,
                                                      int* __restrict__ out,
                                                      int* __restrict__ part, int n) {
    __shared__ int tmp[SCAN_B];
    int t = threadIdx.x, g = blockIdx.x * SCAN_B + t;
    int v = (g < n) ? in[g] : 0;
    tmp[t] = v;
    __syncthreads();
    for (int off = 1; off < SCAN_B; off <<= 1) {
        int add = (t >= off) ? tmp[t - off] : 0;
        __syncthreads();
        tmp[t] += add;
        __syncthreads();
    }
    if (g < n) out[g] = tmp[t] - v;
    if (t == SCAN_B - 1) part[blockIdx.x] = tmp[t];
}

__global__ __launch_bounds__(SCAN_B) void scan_part(int* __restrict__ part, int n) {
    __shared__ int tmp[SCAN_B];
    int t = threadIdx.x;
    int v = (t < n) ? part[t] : 0;
    tmp[t] = v;
    __syncthreads();
    for (int off = 1; off < SCAN_B; off <<= 1) {
        int add = (t >= off) ? tmp[t - off] : 0;
        __syncthreads();
        tmp[t] += add;
        __syncthreads();
    }
    if (t < n) part[t] = tmp[t] - v;
}

__global__ __launch_bounds__(256) void add_off(int* __restrict__ rowptr,
                                               int* __restrict__ cursor,
                                               const int* __restrict__ part,
                                               int* __restrict__ csr_src,
                                               int n, int E) {
    int g = blockIdx.x * blockDim.x + threadIdx.x;
    if (g < n) {
        int v = rowptr[g] + part[g / SCAN_B];
        rowptr[g] = v;
        cursor[g] = v;
    }
    if (g == 0) rowptr[n] = E;
    if (g < 8) csr_src[E + g] = 0;   // pad: valid node id
}

__global__ __launch_bounds__(256) void scatter_k(const int* __restrict__ src,
                                                 const int* __restrict__ dst,
                                                 int* __restrict__ cursor,
                                                 int* __restrict__ csr_src, int E) {
    int e = blockIdx.x * blockDim.x + threadIdx.x;
    if (e < E) {
        int p = atomicAdd(&cursor[dst[e]], 1);
        csr_src[p] = src[e];
    }
}

// ---------------- fused GAT aggregation H=8: broadcast sn preload, early gathers ----------------
template <bool HAS_INIT>
__global__ __launch_bounds__(256) void gat_agg8(const unsigned short* __restrict__ f,
                                                const float* __restrict__ el,
                                                const float* __restrict__ er,
                                                const int* __restrict__ rowptr,
                                                const int* __restrict__ csr_src,
                                                const unsigned short* __restrict__ init,
                                                const float* __restrict__ bias,
                                                unsigned short* __restrict__ outb, int N) {
    int w = (blockIdx.x * blockDim.x + threadIdx.x) >> 6;
    int lane = threadIdx.x & 63;
    if (w >= N) return;
    const int d = w;
    const int s0 = rowptr[d], s1 = rowptr[d + 1];
    const int hh = lane & 7;      // head for score lanes
    const int esub = lane >> 3;   // edge sub-index for score lanes
    const int myhead = lane >> 3; // head for gather lanes
    const int sl8 = lane * 8;
    const float erh = er[(size_t)d * 8 + hh];

    // preload 8 src ids (uniform address across lanes -> broadcast), no cross-lane dep
    int snj[8];
#pragma unroll
    for (int j = 0; j < 8; ++j)
        snj[j] = csr_src[(s0 + j < s1) ? (s0 + j) : N_EDGES];
    // issue all 8 row gathers immediately
    uint4 pk[8];
#pragma unroll
    for (int j = 0; j < 8; ++j)
        pk[j] = *(const uint4*)&f[(size_t)snj[j] * 512 + sl8];

    // softmax (concurrent with in-flight gathers)
    bool valid0 = s0 + esub < s1;
    float v0 = el[(size_t)snj[esub] * 8 + hh] + erh;
    v0 = v0 > 0.f ? v0 : 0.2f * v0;
    float mx = valid0 ? v0 : -1e30f;
    for (int i = s0 + 8 + esub; i < s1; i += 8) {
        float v = el[(size_t)csr_src[i] * 8 + hh] + erh;
        v = v > 0.f ? v : 0.2f * v;
        mx = fmaxf(mx, v);
    }
    mx = fmaxf(mx, __shfl_xor(mx, 8));
    mx = fmaxf(mx, __shfl_xor(mx, 16));
    mx = fmaxf(mx, __shfl_xor(mx, 32));

    float am0 = valid0 ? __expf(v0 - mx) : 0.f;  // unnormalized
    float sm = am0;
    float acc[8] = {};
#pragma unroll
    for (int j = 0; j < 8; ++j) {
        float alpha = __shfl(am0, (j << 3) | myhead);
        acc[0] += blo(pk[j].x) * alpha;
        acc[1] += bhi(pk[j].x) * alpha;
        acc[2] += blo(pk[j].y) * alpha;
        acc[3] += bhi(pk[j].y) * alpha;
        acc[4] += blo(pk[j].z) * alpha;
        acc[5] += bhi(pk[j].z) * alpha;
        acc[6] += blo(pk[j].w) * alpha;
        acc[7] += bhi(pk[j].w) * alpha;
    }

    // remaining chunks (degree > 8)
    for (int ii = s0 + 8; ii < s1; ii += 8) {
        int sn2[8];
#pragma unroll
        for (int j = 0; j < 8; ++j)
            sn2[j] = csr_src[(ii + j < s1) ? (ii + j) : N_EDGES];
        uint4 qk[8];
#pragma unroll
        for (int j = 0; j < 8; ++j)
            qk[j] = *(const uint4*)&f[(size_t)sn2[j] * 512 + sl8];
        bool valid = ii + esub < s1;
        float v = el[(size_t)sn2[esub] * 8 + hh] + erh;
        v = v > 0.f ? v : 0.2f * v;
        float am = valid ? __expf(v - mx) : 0.f;
        sm += am;
#pragma unroll
        for (int j = 0; j < 8; ++j) {
            float alpha = __shfl(am, (j << 3) | myhead);
            acc[0] += blo(qk[j].x) * alpha;
            acc[1] += bhi(qk[j].x) * alpha;
            acc[2] += blo(qk[j].y) * alpha;
            acc[3] += bhi(qk[j].y) * alpha;
            acc[4] += blo(qk[j].z) * alpha;
            acc[5] += bhi(qk[j].z) * alpha;
            acc[6] += blo(qk[j].w) * alpha;
            acc[7] += bhi(qk[j].w) * alpha;
        }
    }

    // normalize
    sm += __shfl_xor(sm, 8);
    sm += __shfl_xor(sm, 16);
    sm += __shfl_xor(sm, 32);
    float smh = __shfl(sm, myhead);
    float inv = smh > 0.f ? 1.0f / smh : 0.f;
#pragma unroll
    for (int j = 0; j < 8; ++j) acc[j] *= inv;

    // epilogue
    const int sl = (lane & 7) * 8;
    float4 b0 = *(const float4*)&bias[myhead * 64 + sl];
    float4 b1 = *(const float4*)&bias[myhead * 64 + sl + 4];
    float bb[8] = {b0.x, b0.y, b0.z, b0.w, b1.x, b1.y, b1.z, b1.w};
    if (HAS_INIT) {
        uint4 iv = *(const uint4*)&init[(size_t)d * 512 + sl8];
        acc[0] += blo(iv.x); acc[1] += bhi(iv.x);
        acc[2] += blo(iv.y); acc[3] += bhi(iv.y);
        acc[4] += blo(iv.z); acc[5] += bhi(iv.z);
        acc[6] += blo(iv.w); acc[7] += bhi(iv.w);
    }
    unsigned short ob[8];
#pragma unroll
    for (int j = 0; j < 8; ++j) {
        float v = acc[j] + bb[j];
        v = v > 0.f ? v : __expf(v) - 1.f;
        ob[j] = f2b(v);
    }
    uint4 ov;
    ov.x = (unsigned)ob[0] | ((unsigned)ob[1] << 16);
    ov.y = (unsigned)ob[2] | ((unsigned)ob[3] << 16);
    ov.z = (unsigned)ob[4] | ((unsigned)ob[5] << 16);
    ov.w = (unsigned)ob[6] | ((unsigned)ob[7] << 16);
    *(uint4*)&outb[(size_t)d * 512 + sl8] = ov;
}

// ---------------- fused GAT aggregation H=1 (layer 3) ----------------
__global__ __launch_bounds__(256) void gat_agg1(const unsigned short* __restrict__ f, // [*,128]
                                                const float* __restrict__ el,
                                                const float* __restrict__ er,
                                                const int* __restrict__ rowptr,
                                                const int* __restrict__ csr_src,
                                                const float* __restrict__ bias,
                                                float* __restrict__ outf, int N) {
    int w = (blockIdx.x * blockDim.x + threadIdx.x) >> 6;
    int lane = threadIdx.x & 63;
    if (w >= N) return;
    const int d = w;
    const int s0 = rowptr[d], s1 = rowptr[d + 1];
    const int esub = lane >> 3, sl = (lane & 7) * 8;
    const float erh = er[d];

    int snj[8];
#pragma unroll
    for (int j = 0; j < 8; ++j)
        snj[j] = csr_src[(s0 + j < s1) ? (s0 + j) : N_EDGES];
    int sn0 = snj[esub];
    uint4 pk0 = *(const uint4*)&f[(size_t)sn0 * 128 + sl];

    bool valid0 = s0 + esub < s1;
    float v0 = el[sn0] + erh;
    v0 = v0 > 0.f ? v0 : 0.2f * v0;
    float mx = valid0 ? v0 : -1e30f;
    for (int i = s0 + 8 + esub; i < s1; i += 8) {
        float v = el[csr_src[i]] + erh;
        v = v > 0.f ? v : 0.2f * v;
        mx = fmaxf(mx, v);
    }
    mx = fmaxf(mx, __shfl_xor(mx, 8));
    mx = fmaxf(mx, __shfl_xor(mx, 16));
    mx = fmaxf(mx, __shfl_xor(mx, 32));

    float am0 = valid0 ? __expf(v0 - mx) : 0.f;
    float sm = am0;
    float acc[8];
    acc[0] = blo(pk0.x) * am0; acc[1] = bhi(pk0.x) * am0;
    acc[2] = blo(pk0.y) * am0; acc[3] = bhi(pk0.y) * am0;
    acc[4] = blo(pk0.z) * am0; acc[5] = bhi(pk0.z) * am0;
    acc[6] = blo(pk0.w) * am0; acc[7] = bhi(pk0.w) * am0;

    for (int ii = s0 + 8; ii < s1; ii += 8) {
        int i = ii + esub;
        bool valid = i < s1;
        int sn = csr_src[valid ? i : N_EDGES];
        uint4 pk = *(const uint4*)&f[(size_t)sn * 128 + sl];
        float v = el[sn] + erh;
        v = v > 0.f ? v : 0.2f * v;
        float am = valid ? __expf(v - mx) : 0.f;
        sm += am;
        acc[0] += blo(pk.x) * am; acc[1] += bhi(pk.x) * am;
        acc[2] += blo(pk.y) * am; acc[3] += bhi(pk.y) * am;
        acc[4] += blo(pk.z) * am; acc[5] += bhi(pk.z) * am;
        acc[6] += blo(pk.w) * am; acc[7] += bhi(pk.w) * am;
    }

    sm += __shfl_xor(sm, 8);
    sm += __shfl_xor(sm, 16);
    sm += __shfl_xor(sm, 32);
#pragma unroll
    for (int off = 8; off < 64; off <<= 1)
#pragma unroll
        for (int j = 0; j < 8; ++j) acc[j] += __shfl_xor(acc[j], off);
    float inv = sm > 0.f ? 1.0f / sm : 0.f;

    if (esub == 0) {
        uint4 rv = *(const uint4*)&f[(size_t)d * 128 + 64 + sl];
        float rr[8] = {blo(rv.x), bhi(rv.x), blo(rv.y), bhi(rv.y),
                       blo(rv.z), bhi(rv.z), blo(rv.w), bhi(rv.w)};
#pragma unroll
        for (int j = 0; j < 8; ++j)
            outf[(size_t)d * 64 + sl + j] = acc[j] * inv + bias[sl + j] + rr[j];
    }
}

extern "C" void kernel_launch(void* const* d_in, const int* in_sizes, int n_in,
                              void* d_out, int out_size, void* d_ws, size_t ws_size,
                              hipStream_t stream) {
    const float* x   = (const float*)d_in[0];
    const int*   src = (const int*)d_in[1];
    const int*   dst = (const int*)d_in[2];
    const float* W1  = (const float*)d_in[3];
    const float* al1 = (const float*)d_in[4];
    const float* ar1 = (const float*)d_in[5];
    const float* b1  = (const float*)d_in[6];
    const float* W2  = (const float*)d_in[7];
    const float* al2 = (const float*)d_in[8];
    const float* ar2 = (const float*)d_in[9];
    const float* b2  = (const float*)d_in[10];
    const float* W3  = (const float*)d_in[11];
    const float* al3 = (const float*)d_in[12];
    const float* ar3 = (const float*)d_in[13];
    const float* b3  = (const float*)d_in[14];
    const float* Wr3 = (const float*)d_in[15];
    float* out = (float*)d_out;

    unsigned short* xb   = (unsigned short*)d_ws;               // [M_PAD][256]
    unsigned short* fb   = xb + (size_t)M_PAD * 256;            // [M_PAD][512]
    unsigned short* h1b  = fb + (size_t)M_PAD * 512;            // [M_PAD][512]
    unsigned short* h2b  = h1b + (size_t)M_PAD * 512;           // [M_PAD][512]
    unsigned short* f3r  = h2b + (size_t)M_PAD * 512;           // [M_PAD][128]
    unsigned short* Wt1  = f3r + (size_t)M_PAD * 128;           // [512][256]
    unsigned short* Wt2  = Wt1 + 512 * 256;                     // [512][512]
    unsigned short* Wt3  = Wt2 + 512 * 512;                     // [128][512]
    float* el = (float*)(Wt3 + 128 * 512);                      // N*8
    float* er = el + (size_t)N_NODES * 8;                       // N*8
    int* rowptr  = (int*)(er + (size_t)N_NODES * 8);            // N+1
    int* cursor  = rowptr + (N_NODES + 1);
    int* part    = cursor + N_NODES;
    int* csr_src = part + 256;                                  // E + 8 pad

    const dim3 blk(256);
    const int E = N_EDGES, N = N_NODES;
    const int nb = (N + SCAN_B - 1) / SCAN_B;
    const int gy = (N + 127) / 128;   // 391

    hipMemsetAsync(cursor, 0, (size_t)N * 4, stream);
    prep_k<<<(X4_N + WTOT + E + 255) / 256, blk, 0, stream>>>(
        x, W1, W2, W3, Wr3, dst, xb, Wt1, Wt2, Wt3, cursor);
    scan_blocks<<<nb, SCAN_B, 0, stream>>>(cursor, rowptr, part, N);
    scan_part<<<1, SCAN_B, 0, stream>>>(part, nb);
    add_off<<<nb, blk, 0, stream>>>(rowptr, cursor, part, csr_src, N, E);
    scatter_k<<<(E + 255) / 256, blk, 0, stream>>>(src, dst, cursor, csr_src, E);

    // ================= layer 1 =================
    gemm_mfma<8, 4, true><<<4 * gy, blk, 0, stream>>>(
        xb, Wt1, fb, al1, ar1, el, er, N, 512, 256);
    gat_agg8<false><<<(N + 3) / 4, blk, 0, stream>>>(
        fb, el, er, rowptr, csr_src, nullptr, b1, h1b, N);

    // ================= layer 2 (identity residual = h1) =================
    gemm_mfma<8, 4, true><<<4 * gy, blk, 0, stream>>>(
        h1b, Wt2, fb, al2, ar2, el, er, N, 512, 512);
    gat_agg8<true><<<(N + 3) / 4, blk, 0, stream>>>(
        fb, el, er, rowptr, csr_src, h1b, b2, h2b, N);

    // ================= layer 3 (1 head, projected residual) =================
    gemm_mfma<1, 1, true><<<gy, blk, 0, stream>>>(
        h2b, Wt3, f3r, al3, ar3, el, er, N, 128, 512);
    gat_agg1<<<(N + 3) / 4, blk, 0, stream>>>(
        f3r, el, er, rowptr, csr_src, b3, out, N);
}